// Round 6
// baseline (2297.358 us; speedup 1.0000x reference)
//
#include <hip/hip_runtime.h>
#include <stdint.h>

typedef unsigned short u16;
using bf16x8 = __attribute__((ext_vector_type(8))) short;
using f32x4  = __attribute__((ext_vector_type(4))) float;

#define N_TOK 2048
#define DMODEL 1024
#define NHEAD 16
#define HDK 64
#define TOPK_K 128

// ---------------- numeric helpers ----------------
__device__ __forceinline__ u16 f2b(float f) {  // fp32 -> bf16 RNE
  unsigned u = __float_as_uint(f);
  return (u16)((u + 0x7FFFu + ((u >> 16) & 1u)) >> 16);
}
__device__ __forceinline__ float b2f(u16 b) {
  return __uint_as_float(((unsigned)b) << 16);
}
__device__ __forceinline__ float wave_reduce_max(float v) {
#pragma unroll
  for (int d = 32; d >= 1; d >>= 1) v = fmaxf(v, __shfl_xor(v, d));
  return v;
}
__device__ __forceinline__ float wave_reduce_sum(float v) {
#pragma unroll
  for (int d = 32; d >= 1; d >>= 1) v += __shfl_xor(v, d);
  return v;
}
__device__ __forceinline__ unsigned f2key(float f) {  // order-preserving
  unsigned u = __float_as_uint(f);
  return (u & 0x80000000u) ? ~u : (u | 0x80000000u);
}

// ---------------- LayerNorm -> bf16 ----------------
__global__ __launch_bounds__(256) void ln_kernel(const float* __restrict__ x,
                                                 const float* __restrict__ gamma,
                                                 const float* __restrict__ beta,
                                                 u16* __restrict__ xn) {
  int w = threadIdx.x >> 6, lane = threadIdx.x & 63;
  int row = blockIdx.x * 4 + w;
  const float4* xr = (const float4*)(x + (size_t)row * DMODEL);
  float4 v[4];
  float s = 0.f, ss = 0.f;
#pragma unroll
  for (int i = 0; i < 4; ++i) {
    v[i] = xr[i * 64 + lane];
    s += v[i].x + v[i].y + v[i].z + v[i].w;
    ss += v[i].x * v[i].x + v[i].y * v[i].y + v[i].z * v[i].z + v[i].w * v[i].w;
  }
  s = wave_reduce_sum(s);
  ss = wave_reduce_sum(ss);
  float mu = s * (1.f / DMODEL);
  float var = ss * (1.f / DMODEL) - mu * mu;
  float rstd = rsqrtf(var + 1e-5f);
  const float4* g4 = (const float4*)gamma;
  const float4* b4 = (const float4*)beta;
  u16* xo = xn + (size_t)row * DMODEL;
#pragma unroll
  for (int i = 0; i < 4; ++i) {
    float4 g = g4[i * 64 + lane], b = b4[i * 64 + lane];
    float ox = (v[i].x - mu) * rstd * g.x + b.x;
    float oy = (v[i].y - mu) * rstd * g.y + b.y;
    float oz = (v[i].z - mu) * rstd * g.z + b.z;
    float ow = (v[i].w - mu) * rstd * g.w + b.w;
    unsigned lo = (unsigned)f2b(ox) | ((unsigned)f2b(oy) << 16);
    unsigned hi = (unsigned)f2b(oz) | ((unsigned)f2b(ow) << 16);
    *(uint2*)&xo[(i * 64 + lane) * 4] = make_uint2(lo, hi);
  }
}

// ---------------- fp32 -> bf16 cast (n8 = elems/8) ----------------
__global__ __launch_bounds__(256) void cast_kernel(const float* __restrict__ in,
                                                   u16* __restrict__ out, int n8) {
  int i = blockIdx.x * 256 + threadIdx.x;
  if (i >= n8) return;
  const float4* p = (const float4*)in + (size_t)i * 2;
  float4 a = p[0], b = p[1];
  unsigned w0 = (unsigned)f2b(a.x) | ((unsigned)f2b(a.y) << 16);
  unsigned w1 = (unsigned)f2b(a.z) | ((unsigned)f2b(a.w) << 16);
  unsigned w2 = (unsigned)f2b(b.x) | ((unsigned)f2b(b.y) << 16);
  unsigned w3 = (unsigned)f2b(b.z) | ((unsigned)f2b(b.w) << 16);
  *(uint4*)&out[(size_t)i * 8] = make_uint4(w0, w1, w2, w3);
}

// ---------------- V (2048x1024) -> Vt (1024x2048) bf16 transpose ----------------
__global__ __launch_bounds__(256) void transpose_kernel(const u16* __restrict__ V,
                                                        u16* __restrict__ Vt) {
  __shared__ u16 tile[64][72];
  int kb = blockIdx.x * 64, cb = blockIdx.y * 64;
  int t = threadIdx.x;
  int r = t >> 2, cg = (t & 3) * 16;
  *(uint4*)&tile[r][cg]     = *(const uint4*)&V[(size_t)(kb + r) * DMODEL + cb + cg];
  *(uint4*)&tile[r][cg + 8] = *(const uint4*)&V[(size_t)(kb + r) * DMODEL + cb + cg + 8];
  __syncthreads();
  int c = t >> 2, kg = (t & 3) * 16;
  size_t base = (size_t)(cb + c) * N_TOK + kb + kg;
  unsigned p0 = (unsigned)tile[kg + 0][c] | ((unsigned)tile[kg + 1][c] << 16);
  unsigned p1 = (unsigned)tile[kg + 2][c] | ((unsigned)tile[kg + 3][c] << 16);
  unsigned p2 = (unsigned)tile[kg + 4][c] | ((unsigned)tile[kg + 5][c] << 16);
  unsigned p3 = (unsigned)tile[kg + 6][c] | ((unsigned)tile[kg + 7][c] << 16);
  unsigned p4 = (unsigned)tile[kg + 8][c] | ((unsigned)tile[kg + 9][c] << 16);
  unsigned p5 = (unsigned)tile[kg + 10][c] | ((unsigned)tile[kg + 11][c] << 16);
  unsigned p6 = (unsigned)tile[kg + 12][c] | ((unsigned)tile[kg + 13][c] << 16);
  unsigned p7 = (unsigned)tile[kg + 14][c] | ((unsigned)tile[kg + 15][c] << 16);
  *(uint4*)&Vt[base]     = make_uint4(p0, p1, p2, p3);
  *(uint4*)&Vt[base + 8] = make_uint4(p4, p5, p6, p7);
}

// ---------------- bf16 MFMA GEMM: C = scale*(A . B^T) [+bias] [+res] ----------------
__global__ __launch_bounds__(256) void gemm_bf16_nt(
    const u16* __restrict__ A, int lda, int az,
    const u16* __restrict__ B, int ldb, int bz,
    void* __restrict__ Cv, int ldc, int cz,
    int K, float scale,
    const float* __restrict__ bias,
    const float* __restrict__ res, int out_f32) {
  __shared__ u16 As[64 * 40];  // row stride 40 bf16 (80 B): 16B-aligned, 2-way max
  __shared__ u16 Bs[64 * 40];
  A += (size_t)blockIdx.z * az;
  B += (size_t)blockIdx.z * bz;
  int bi = blockIdx.y * 64, bj = blockIdx.x * 64;
  int tid = threadIdx.x;
  int w = tid >> 6, lane = tid & 63;
  int wr = w >> 1, wc = w & 1;
  int lr = tid >> 2, lc = (tid & 3) * 8;
  int kh = (lane >> 4) * 8, fr = lane & 15;
  f32x4 acc[2][2] = {};
  for (int k0 = 0; k0 < K; k0 += 32) {
    *(uint4*)&As[lr * 40 + lc] = *(const uint4*)&A[(size_t)(bi + lr) * lda + k0 + lc];
    *(uint4*)&Bs[lr * 40 + lc] = *(const uint4*)&B[(size_t)(bj + lr) * ldb + k0 + lc];
    __syncthreads();
    bf16x8 a0 = *(bf16x8*)&As[(wr * 32 + fr) * 40 + kh];
    bf16x8 a1 = *(bf16x8*)&As[(wr * 32 + 16 + fr) * 40 + kh];
    bf16x8 b0 = *(bf16x8*)&Bs[(wc * 32 + fr) * 40 + kh];
    bf16x8 b1 = *(bf16x8*)&Bs[(wc * 32 + 16 + fr) * 40 + kh];
    acc[0][0] = __builtin_amdgcn_mfma_f32_16x16x32_bf16(a0, b0, acc[0][0], 0, 0, 0);
    acc[0][1] = __builtin_amdgcn_mfma_f32_16x16x32_bf16(a0, b1, acc[0][1], 0, 0, 0);
    acc[1][0] = __builtin_amdgcn_mfma_f32_16x16x32_bf16(a1, b0, acc[1][0], 0, 0, 0);
    acc[1][1] = __builtin_amdgcn_mfma_f32_16x16x32_bf16(a1, b1, acc[1][1], 0, 0, 0);
    __syncthreads();
  }
  float* Cf = (float*)Cv + (size_t)blockIdx.z * cz;
  u16* Ch = (u16*)Cv + (size_t)blockIdx.z * cz;
  int rg = (lane >> 4) * 4;
#pragma unroll
  for (int m = 0; m < 2; ++m) {
#pragma unroll
    for (int n = 0; n < 2; ++n) {
      int gcol = bj + wc * 32 + n * 16 + fr;
      float badd = bias ? bias[gcol] : 0.f;
#pragma unroll
      for (int r = 0; r < 4; ++r) {
        int grow = bi + wr * 32 + m * 16 + rg + r;
        size_t off = (size_t)grow * ldc + gcol;
        float v = acc[m][n][r] * scale + badd;
        if (res) v += res[off];
        if (out_f32) Cf[off] = v;
        else Ch[off] = f2b(v);
      }
    }
  }
}

// ---------------- Fused: pre-mix -> softmax -> exact top-k -> renorm -> post-mix ----
// One block per query. S (bf16) layout (q, h, k). ALL score state lives in LDS;
// no long-lived register arrays (round-5 counters: v[32] spilled -> 5.5 GB scratch HBM).
__global__ __launch_bounds__(1024, 4) void fused_rows_kernel(
    u16* __restrict__ S,
    const float* __restrict__ Wpre, const float* __restrict__ Wpost,
    const float* __restrict__ bpost) {
  __shared__ float row[NHEAD][N_TOK];   // 128 KB
  __shared__ unsigned hist[NHEAD][258];
  __shared__ float wpre_s[256], wpost_s[256], bpost_s[16];
  int tid = threadIdx.x;
  size_t qbase = (size_t)blockIdx.x * (NHEAD * N_TOK);
  if (tid < 256) { wpre_s[tid] = Wpre[tid]; wpost_s[tid] = Wpost[tid]; }
  if (tid >= 256 && tid < 272) bpost_s[tid - 256] = bpost[tid - 256];
  const u16* gS = S + qbase;
  float* rflat = &row[0][0];
#pragma unroll
  for (int i = 0; i < 4; ++i) {
    int e0 = (i * 1024 + tid) * 8;
    uint4 pk = *(const uint4*)&gS[e0];
    rflat[e0 + 0] = __uint_as_float(pk.x << 16);
    rflat[e0 + 1] = __uint_as_float(pk.x & 0xFFFF0000u);
    rflat[e0 + 2] = __uint_as_float(pk.y << 16);
    rflat[e0 + 3] = __uint_as_float(pk.y & 0xFFFF0000u);
    rflat[e0 + 4] = __uint_as_float(pk.z << 16);
    rflat[e0 + 5] = __uint_as_float(pk.z & 0xFFFF0000u);
    rflat[e0 + 6] = __uint_as_float(pk.w << 16);
    rflat[e0 + 7] = __uint_as_float(pk.w & 0xFFFF0000u);
  }
  __syncthreads();

  // pre talking-heads mix, in place per column (transient regs only)
#pragma unroll
  for (int c0 = 0; c0 < N_TOK; c0 += 1024) {
    int c = c0 + tid;
    float sv[16], mv[16];
#pragma unroll
    for (int h = 0; h < 16; ++h) sv[h] = row[h][c];
#pragma unroll
    for (int g = 0; g < 16; ++g) {
      float a = 0.f;
#pragma unroll
      for (int h = 0; h < 16; ++h) a = fmaf(wpre_s[g * 16 + h], sv[h], a);
      mv[g] = a;
    }
#pragma unroll
    for (int g = 0; g < 16; ++g) row[g][c] = mv[g];
  }
  __syncthreads();

  int w = tid >> 6, lane = tid & 63;
  float* rw = row[w];

  // softmax stats, straight from LDS
  float mx = -3.402823466e38f;
#pragma unroll
  for (int j = 0; j < 32; ++j) mx = fmaxf(mx, rw[lane + (j << 6)]);
  mx = wave_reduce_max(mx);
  float z = 0.f;
#pragma unroll
  for (int j = 0; j < 32; ++j) z += __expf(rw[lane + (j << 6)] - mx);
  z = wave_reduce_sum(z);

  // exact 128th-largest via 4-pass radix select (wave-private hist, values from LDS)
  unsigned prefix = 0;
  int remaining = TOPK_K;
  unsigned* hw = hist[w];
#pragma unroll 1
  for (int pass = 0; pass < 4; ++pass) {
    int shift = 24 - (pass << 3);
    for (int b = lane; b < 256; b += 64) hw[b] = 0;
    __syncthreads();
#pragma unroll
    for (int j = 0; j < 32; ++j) {
      unsigned k = f2key(rw[lane + (j << 6)]);
      bool in = (pass == 0) || ((k >> (shift + 8)) == (prefix >> (shift + 8)));
      if (in) atomicAdd(&hw[(k >> shift) & 255], 1u);
    }
    __syncthreads();
    unsigned hh[4];
#pragma unroll
    for (int b = 0; b < 4; ++b) hh[b] = hw[(lane << 2) + b];
    unsigned csum = hh[0] + hh[1] + hh[2] + hh[3];
    unsigned suf = csum;
#pragma unroll
    for (int d = 1; d < 64; d <<= 1) {
      unsigned o = __shfl_down(suf, d);
      if (lane + d < 64) suf += o;
    }
    unsigned above = suf - csum;  // count with digit >= 4*(lane+1)
    int fdig = -1, frem = 0;
    unsigned cum = above;
#pragma unroll
    for (int b = 3; b >= 0; --b) {
      if (fdig < 0 && cum + hh[b] >= (unsigned)remaining) {
        fdig = (lane << 2) + b;
        frem = remaining - (int)cum;
      } else if (fdig < 0) {
        cum += hh[b];
      }
    }
    unsigned long long ball = __ballot(fdig >= 0);
    int src = 63 - (int)__clzll(ball);  // threshold digit is in the HIGHEST firing lane
    int dig = __shfl(fdig, src);
    remaining = __shfl(frem, src);
    prefix |= ((unsigned)dig) << shift;
    __syncthreads();
  }

  // masked sum (mask: key >= prefix  <=>  attn >= kth, ties kept)
  float invZ = 1.f / z;
  float msum = 0.f;
#pragma unroll
  for (int j = 0; j < 32; ++j) {
    float s = rw[lane + (j << 6)];
    if (f2key(s) >= prefix) msum += __expf(s - mx) * invZ;
  }
  msum = wave_reduce_sum(msum);
  float scaleP = invZ / (msum + 1e-9f);

  // sparse renorm write-back into LDS
#pragma unroll
  for (int j = 0; j < 32; ++j) {
    float s = rw[lane + (j << 6)];
    rw[lane + (j << 6)] = (f2key(s) >= prefix) ? __expf(s - mx) * scaleP : 0.f;
  }
  __syncthreads();

  // post talking-heads mix (+bpost) -> bf16 attn2 in place over S
  u16* gout = S + qbase;
#pragma unroll
  for (int c0 = 0; c0 < N_TOK; c0 += 1024) {
    int c = c0 + tid;
    float sv[16];
#pragma unroll
    for (int h = 0; h < 16; ++h) sv[h] = row[h][c];
#pragma unroll
    for (int g = 0; g < 16; ++g) {
      float a = bpost_s[g];
#pragma unroll
      for (int h = 0; h < 16; ++h) a = fmaf(wpost_s[g * 16 + h], sv[h], a);
      gout[g * N_TOK + c] = f2b(a);
    }
  }
}

// ---------------- launch ----------------
extern "C" void kernel_launch(void* const* d_in, const int* in_sizes, int n_in,
                              void* d_out, int out_size, void* d_ws, size_t ws_size,
                              hipStream_t stream) {
  const float* x     = (const float*)d_in[0];
  const float* Wq    = (const float*)d_in[1];
  const float* bq    = (const float*)d_in[2];
  const float* Wk    = (const float*)d_in[3];
  const float* bk    = (const float*)d_in[4];
  const float* Wv    = (const float*)d_in[5];
  const float* bv    = (const float*)d_in[6];
  const float* Wpre  = (const float*)d_in[7];
  // d_in[8] = bpre: no-op (softmax shift-invariant; top-k order unchanged)
  const float* Wpost = (const float*)d_in[9];
  const float* bpost = (const float*)d_in[10];
  const float* Wo    = (const float*)d_in[11];
  const float* bo    = (const float*)d_in[12];
  const float* gamma = (const float*)d_in[13];
  const float* beta  = (const float*)d_in[14];

  const size_t NM = (size_t)N_TOK * DMODEL;   // 2M
  const size_t WW = (size_t)DMODEL * DMODEL;  // 1M
  char* p = (char*)d_ws;
  u16* xnb = (u16*)p; p += NM * 2;
  u16* Qb  = (u16*)p; p += NM * 2;
  u16* Kb  = (u16*)p; p += NM * 2;
  u16* Vb  = (u16*)p; p += NM * 2;
  u16* Vtb = (u16*)p; p += NM * 2;
  u16* AOb = (u16*)p; p += NM * 2;
  u16* Wqb = (u16*)p; p += WW * 2;
  u16* Wkb = (u16*)p; p += WW * 2;
  u16* Wvb = (u16*)p; p += WW * 2;
  u16* Wob = (u16*)p; p += WW * 2;
  u16* S   = (u16*)p;
  size_t base = (size_t)(p - (char*)d_ws);

  int CQ = 0;
  const int cands[6] = {2048, 1024, 512, 256, 128, 64};
  for (int i = 0; i < 6; ++i) {
    if (base + (size_t)cands[i] * NHEAD * N_TOK * 2 <= ws_size) { CQ = cands[i]; break; }
  }
  if (CQ == 0) return;

  ln_kernel<<<N_TOK / 4, 256, 0, stream>>>(x, gamma, beta, xnb);
  cast_kernel<<<512, 256, 0, stream>>>(Wq, Wqb, WW / 8);
  cast_kernel<<<512, 256, 0, stream>>>(Wk, Wkb, WW / 8);
  cast_kernel<<<512, 256, 0, stream>>>(Wv, Wvb, WW / 8);
  cast_kernel<<<512, 256, 0, stream>>>(Wo, Wob, WW / 8);

  gemm_bf16_nt<<<dim3(16, 32, 1), 256, 0, stream>>>(xnb, DMODEL, 0, Wqb, DMODEL, 0,
                                                    Qb, DMODEL, 0, DMODEL, 1.f, bq, nullptr, 0);
  gemm_bf16_nt<<<dim3(16, 32, 1), 256, 0, stream>>>(xnb, DMODEL, 0, Wkb, DMODEL, 0,
                                                    Kb, DMODEL, 0, DMODEL, 1.f, bk, nullptr, 0);
  gemm_bf16_nt<<<dim3(16, 32, 1), 256, 0, stream>>>(xnb, DMODEL, 0, Wvb, DMODEL, 0,
                                                    Vb, DMODEL, 0, DMODEL, 1.f, bv, nullptr, 0);
  transpose_kernel<<<dim3(N_TOK / 64, DMODEL / 64), 256, 0, stream>>>(Vb, Vtb);

  for (int q0 = 0; q0 < N_TOK; q0 += CQ) {
    // scores: S[ql][h][k] = 0.125 * Q_h[q0+ql] . K_h^T   (bf16 out)
    gemm_bf16_nt<<<dim3(N_TOK / 64, CQ / 64, NHEAD), 256, 0, stream>>>(
        Qb + (size_t)q0 * DMODEL, DMODEL, HDK, Kb, DMODEL, HDK,
        S, NHEAD * N_TOK, N_TOK, HDK, 0.125f, nullptr, nullptr, 0);

    fused_rows_kernel<<<CQ, 1024, 0, stream>>>(S, Wpre, Wpost, bpost);

    // PV: AO[q0+ql][h*64+d] = attn2[ql][h][:] . Vt_h[d][:]   (bf16 out)
    gemm_bf16_nt<<<dim3(1, CQ / 64, NHEAD), 256, 0, stream>>>(
        S, NHEAD * N_TOK, N_TOK, Vtb, N_TOK, HDK * N_TOK,
        AOb + (size_t)q0 * DMODEL, DMODEL, HDK, N_TOK, 1.f, nullptr, nullptr, 0);
  }

  // out = AO @ Wo^T + bo + x   (fp32 out)
  gemm_bf16_nt<<<dim3(16, 32, 1), 256, 0, stream>>>(AOb, DMODEL, 0, Wob, DMODEL, 0,
                                                    d_out, DMODEL, 0, DMODEL, 1.f, bo, x, 1);
}

// Round 7
// 580.627 us; speedup vs baseline: 3.9567x; 3.9567x over previous
//
#include <hip/hip_runtime.h>
#include <stdint.h>

typedef unsigned short u16;
using bf16x8 = __attribute__((ext_vector_type(8))) short;
using f32x4  = __attribute__((ext_vector_type(4))) float;

#define N_TOK 2048
#define DMODEL 1024
#define NHEAD 16
#define HDK 64
#define TOPK_K 128

// ---------------- numeric helpers ----------------
__device__ __forceinline__ u16 f2b(float f) {  // fp32 -> bf16 RNE
  unsigned u = __float_as_uint(f);
  return (u16)((u + 0x7FFFu + ((u >> 16) & 1u)) >> 16);
}
__device__ __forceinline__ float b2f(u16 b) {
  return __uint_as_float(((unsigned)b) << 16);
}
__device__ __forceinline__ float wave_reduce_sum(float v) {
#pragma unroll
  for (int d = 32; d >= 1; d >>= 1) v += __shfl_xor(v, d);
  return v;
}
// order-preserving fp32-bits -> uint key (ascending float -> ascending uint)
__device__ __forceinline__ unsigned bits2key(unsigned u) {
  return (u & 0x80000000u) ? ~u : (u | 0x80000000u);
}
__device__ __forceinline__ float key2f(unsigned k) {
  unsigned u = (k & 0x80000000u) ? (k ^ 0x80000000u) : ~k;
  return __uint_as_float(u);
}

// ---------------- LayerNorm -> bf16 ----------------
__global__ __launch_bounds__(256) void ln_kernel(const float* __restrict__ x,
                                                 const float* __restrict__ gamma,
                                                 const float* __restrict__ beta,
                                                 u16* __restrict__ xn) {
  int w = threadIdx.x >> 6, lane = threadIdx.x & 63;
  int row = blockIdx.x * 4 + w;
  const float4* xr = (const float4*)(x + (size_t)row * DMODEL);
  float4 v[4];
  float s = 0.f, ss = 0.f;
#pragma unroll
  for (int i = 0; i < 4; ++i) {
    v[i] = xr[i * 64 + lane];
    s += v[i].x + v[i].y + v[i].z + v[i].w;
    ss += v[i].x * v[i].x + v[i].y * v[i].y + v[i].z * v[i].z + v[i].w * v[i].w;
  }
  s = wave_reduce_sum(s);
  ss = wave_reduce_sum(ss);
  float mu = s * (1.f / DMODEL);
  float var = ss * (1.f / DMODEL) - mu * mu;
  float rstd = rsqrtf(var + 1e-5f);
  const float4* g4 = (const float4*)gamma;
  const float4* b4 = (const float4*)beta;
  u16* xo = xn + (size_t)row * DMODEL;
#pragma unroll
  for (int i = 0; i < 4; ++i) {
    float4 g = g4[i * 64 + lane], b = b4[i * 64 + lane];
    float ox = (v[i].x - mu) * rstd * g.x + b.x;
    float oy = (v[i].y - mu) * rstd * g.y + b.y;
    float oz = (v[i].z - mu) * rstd * g.z + b.z;
    float ow = (v[i].w - mu) * rstd * g.w + b.w;
    unsigned lo = (unsigned)f2b(ox) | ((unsigned)f2b(oy) << 16);
    unsigned hi = (unsigned)f2b(oz) | ((unsigned)f2b(ow) << 16);
    *(uint2*)&xo[(i * 64 + lane) * 4] = make_uint2(lo, hi);
  }
}

// ---------------- fp32 -> bf16 cast (n8 = elems/8) ----------------
__global__ __launch_bounds__(256) void cast_kernel(const float* __restrict__ in,
                                                   u16* __restrict__ out, int n8) {
  int i = blockIdx.x * 256 + threadIdx.x;
  if (i >= n8) return;
  const float4* p = (const float4*)in + (size_t)i * 2;
  float4 a = p[0], b = p[1];
  unsigned w0 = (unsigned)f2b(a.x) | ((unsigned)f2b(a.y) << 16);
  unsigned w1 = (unsigned)f2b(a.z) | ((unsigned)f2b(a.w) << 16);
  unsigned w2 = (unsigned)f2b(b.x) | ((unsigned)f2b(b.y) << 16);
  unsigned w3 = (unsigned)f2b(b.z) | ((unsigned)f2b(b.w) << 16);
  *(uint4*)&out[(size_t)i * 8] = make_uint4(w0, w1, w2, w3);
}

// ---------------- V (2048x1024) -> Vt (1024x2048) bf16 transpose ----------------
__global__ __launch_bounds__(256) void transpose_kernel(const u16* __restrict__ V,
                                                        u16* __restrict__ Vt) {
  __shared__ u16 tile[64][72];
  int kb = blockIdx.x * 64, cb = blockIdx.y * 64;
  int t = threadIdx.x;
  int r = t >> 2, cg = (t & 3) * 16;
  *(uint4*)&tile[r][cg]     = *(const uint4*)&V[(size_t)(kb + r) * DMODEL + cb + cg];
  *(uint4*)&tile[r][cg + 8] = *(const uint4*)&V[(size_t)(kb + r) * DMODEL + cb + cg + 8];
  __syncthreads();
  int c = t >> 2, kg = (t & 3) * 16;
  size_t base = (size_t)(cb + c) * N_TOK + kb + kg;
  unsigned p0 = (unsigned)tile[kg + 0][c] | ((unsigned)tile[kg + 1][c] << 16);
  unsigned p1 = (unsigned)tile[kg + 2][c] | ((unsigned)tile[kg + 3][c] << 16);
  unsigned p2 = (unsigned)tile[kg + 4][c] | ((unsigned)tile[kg + 5][c] << 16);
  unsigned p3 = (unsigned)tile[kg + 6][c] | ((unsigned)tile[kg + 7][c] << 16);
  unsigned p4 = (unsigned)tile[kg + 8][c] | ((unsigned)tile[kg + 9][c] << 16);
  unsigned p5 = (unsigned)tile[kg + 10][c] | ((unsigned)tile[kg + 11][c] << 16);
  unsigned p6 = (unsigned)tile[kg + 12][c] | ((unsigned)tile[kg + 13][c] << 16);
  unsigned p7 = (unsigned)tile[kg + 14][c] | ((unsigned)tile[kg + 15][c] << 16);
  *(uint4*)&Vt[base]     = make_uint4(p0, p1, p2, p3);
  *(uint4*)&Vt[base + 8] = make_uint4(p4, p5, p6, p7);
}

// ---------------- bf16 MFMA GEMM: C = scale*(A . B^T) [+bias] [+res] ----------------
__global__ __launch_bounds__(256) void gemm_bf16_nt(
    const u16* __restrict__ A, int lda, int az,
    const u16* __restrict__ B, int ldb, int bz,
    void* __restrict__ Cv, int ldc, int cz,
    int K, float scale,
    const float* __restrict__ bias,
    const float* __restrict__ res, int out_f32) {
  __shared__ u16 As[64 * 40];  // row stride 40 bf16 (80 B): 16B-aligned, 2-way max
  __shared__ u16 Bs[64 * 40];
  A += (size_t)blockIdx.z * az;
  B += (size_t)blockIdx.z * bz;
  int bi = blockIdx.y * 64, bj = blockIdx.x * 64;
  int tid = threadIdx.x;
  int w = tid >> 6, lane = tid & 63;
  int wr = w >> 1, wc = w & 1;
  int lr = tid >> 2, lc = (tid & 3) * 8;
  int kh = (lane >> 4) * 8, fr = lane & 15;
  f32x4 acc[2][2] = {};
  for (int k0 = 0; k0 < K; k0 += 32) {
    *(uint4*)&As[lr * 40 + lc] = *(const uint4*)&A[(size_t)(bi + lr) * lda + k0 + lc];
    *(uint4*)&Bs[lr * 40 + lc] = *(const uint4*)&B[(size_t)(bj + lr) * ldb + k0 + lc];
    __syncthreads();
    bf16x8 a0 = *(bf16x8*)&As[(wr * 32 + fr) * 40 + kh];
    bf16x8 a1 = *(bf16x8*)&As[(wr * 32 + 16 + fr) * 40 + kh];
    bf16x8 b0 = *(bf16x8*)&Bs[(wc * 32 + fr) * 40 + kh];
    bf16x8 b1 = *(bf16x8*)&Bs[(wc * 32 + 16 + fr) * 40 + kh];
    acc[0][0] = __builtin_amdgcn_mfma_f32_16x16x32_bf16(a0, b0, acc[0][0], 0, 0, 0);
    acc[0][1] = __builtin_amdgcn_mfma_f32_16x16x32_bf16(a0, b1, acc[0][1], 0, 0, 0);
    acc[1][0] = __builtin_amdgcn_mfma_f32_16x16x32_bf16(a1, b0, acc[1][0], 0, 0, 0);
    acc[1][1] = __builtin_amdgcn_mfma_f32_16x16x32_bf16(a1, b1, acc[1][1], 0, 0, 0);
    __syncthreads();
  }
  float* Cf = (float*)Cv + (size_t)blockIdx.z * cz;
  u16* Ch = (u16*)Cv + (size_t)blockIdx.z * cz;
  int rg = (lane >> 4) * 4;
#pragma unroll
  for (int m = 0; m < 2; ++m) {
#pragma unroll
    for (int n = 0; n < 2; ++n) {
      int gcol = bj + wc * 32 + n * 16 + fr;
      float badd = bias ? bias[gcol] : 0.f;
#pragma unroll
      for (int r = 0; r < 4; ++r) {
        int grow = bi + wr * 32 + m * 16 + rg + r;
        size_t off = (size_t)grow * ldc + gcol;
        float v = acc[m][n][r] * scale + badd;
        if (res) v += res[off];
        if (out_f32) Cf[off] = v;
        else Ch[off] = f2b(v);
      }
    }
  }
}

// ---------------- M1/M3: head-mix per (q,k) column: out[g] = W[g,:] . in[:] (+bias) ----
// in: bf16 (q,h,k). out_f32 ? fp32 out : bf16 out (may alias in — block stages first).
// grid (CQ, 4); block 256; each block: one q, 512-wide k window.
__global__ __launch_bounds__(256) void headmix_kernel(
    const u16* __restrict__ in, const float* __restrict__ W,
    const float* __restrict__ bias, void* __restrict__ out, int out_f32) {
  __shared__ u16 tile[NHEAD][512];
  __shared__ float w_s[256];
  __shared__ float b_s[16];
  int q = blockIdx.x, kb = blockIdx.y * 512;
  int t = threadIdx.x;
  w_s[t] = W[t];
  if (t < 16) b_s[t] = bias ? bias[t] : 0.f;
#pragma unroll
  for (int j = 0; j < 4; ++j) {
    int idx = j * 256 + t;
    int h = idx >> 6, cu = idx & 63;
    ((uint4*)&tile[h][0])[cu] =
        ((const uint4*)(in + ((size_t)q * NHEAD + h) * N_TOK + kb))[cu];
  }
  __syncthreads();
  float sv0[16], sv1[16];
#pragma unroll
  for (int h = 0; h < 16; ++h) {
    unsigned pw = ((const unsigned*)&tile[h][0])[t];
    sv0[h] = b2f((u16)(pw & 0xFFFFu));
    sv1[h] = b2f((u16)(pw >> 16));
  }
#pragma unroll
  for (int g = 0; g < 16; ++g) {
    float a0 = b_s[g], a1 = b_s[g];
#pragma unroll
    for (int h = 0; h < 16; ++h) {
      float wv = w_s[g * 16 + h];
      a0 = fmaf(wv, sv0[h], a0);
      a1 = fmaf(wv, sv1[h], a1);
    }
    size_t obase = ((size_t)q * NHEAD + g) * N_TOK + kb;
    if (out_f32) {
      ((float2*)((float*)out + obase))[t] = make_float2(a0, a1);
    } else {
      ((unsigned*)((u16*)out + obase))[t] =
          (unsigned)f2b(a0) | ((unsigned)f2b(a1) << 16);
    }
  }
}

// ---------------- M2: per-row softmax + exact top-128 + renorm ----------------
// One WAVE per (q,g) row. In: S2 fp32 rows; out: attn bf16 rows (into S).
// No LDS, no atomics, no syncthreads. 32 keys/lane in registers (static idx only).
__global__ __launch_bounds__(256) void topk_rows_kernel(
    const float* __restrict__ S2, u16* __restrict__ S) {
  int row = blockIdx.x * 4 + (threadIdx.x >> 6);
  int lane = threadIdx.x & 63;
  const uint4* rp = (const uint4*)(S2 + (size_t)row * N_TOK);
  unsigned key[32];
#pragma unroll
  for (int i = 0; i < 8; ++i) {
    uint4 u = rp[i * 64 + lane];
    key[i * 4 + 0] = bits2key(u.x);
    key[i * 4 + 1] = bits2key(u.y);
    key[i * 4 + 2] = bits2key(u.z);
    key[i * 4 + 3] = bits2key(u.w);
  }
  // row max (keys are order-preserving)
  unsigned kmax = 0u;
#pragma unroll
  for (int j = 0; j < 32; ++j) kmax = key[j] > kmax ? key[j] : kmax;
#pragma unroll
  for (int d = 32; d >= 1; d >>= 1) {
    unsigned o = (unsigned)__shfl_xor((int)kmax, d);
    kmax = o > kmax ? o : kmax;
  }
  float mx = key2f(kmax);
  // exact 128th-largest key via binary search (count >= T is monotone in T)
  unsigned T = 0u;
#pragma unroll 1
  for (int bit = 31; bit >= 0; --bit) {
    unsigned cand = T | (1u << bit);
    int c = 0;
#pragma unroll
    for (int j = 0; j < 32; ++j) c += (key[j] >= cand) ? 1 : 0;
#pragma unroll
    for (int d = 32; d >= 1; d >>= 1) c += __shfl_xor(c, d);
    if (c >= TOPK_K) T = cand;
  }
  // z (all) and masked sum (kept: key >= T, ties included)
  float z = 0.f, ms = 0.f;
#pragma unroll
  for (int j = 0; j < 32; ++j) {
    float e = __expf(key2f(key[j]) - mx);
    z += e;
    if (key[j] >= T) ms += e;
  }
  z = wave_reduce_sum(z);
  ms = wave_reduce_sum(ms);
  // out = (e/z) / (ms/z + 1e-9) = e / (ms + 1e-9*z)
  float cs = 1.f / (ms + 1e-9f * z);
  u16* op = S + (size_t)row * N_TOK;
#pragma unroll
  for (int i = 0; i < 8; ++i) {
    unsigned pk[4];
#pragma unroll
    for (int c2 = 0; c2 < 4; ++c2) {
      unsigned k = key[i * 4 + c2];
      float e = (k >= T) ? __expf(key2f(k) - mx) * cs : 0.f;
      pk[c2] = (unsigned)f2b(e);
    }
    uint2 w2;
    w2.x = pk[0] | (pk[1] << 16);
    w2.y = pk[2] | (pk[3] << 16);
    ((uint2*)op)[i * 64 + lane] = w2;
  }
}

// ---------------- launch ----------------
extern "C" void kernel_launch(void* const* d_in, const int* in_sizes, int n_in,
                              void* d_out, int out_size, void* d_ws, size_t ws_size,
                              hipStream_t stream) {
  const float* x     = (const float*)d_in[0];
  const float* Wq    = (const float*)d_in[1];
  const float* bq    = (const float*)d_in[2];
  const float* Wk    = (const float*)d_in[3];
  const float* bk    = (const float*)d_in[4];
  const float* Wv    = (const float*)d_in[5];
  const float* bv    = (const float*)d_in[6];
  const float* Wpre  = (const float*)d_in[7];
  // d_in[8] = bpre: no-op (softmax shift-invariant; top-k order unchanged)
  const float* Wpost = (const float*)d_in[9];
  const float* bpost = (const float*)d_in[10];
  const float* Wo    = (const float*)d_in[11];
  const float* bo    = (const float*)d_in[12];
  const float* gamma = (const float*)d_in[13];
  const float* beta  = (const float*)d_in[14];

  const size_t NM = (size_t)N_TOK * DMODEL;   // 2M
  const size_t WW = (size_t)DMODEL * DMODEL;  // 1M
  char* p = (char*)d_ws;
  u16* xnb = (u16*)p; p += NM * 2;
  u16* Qb  = (u16*)p; p += NM * 2;
  u16* Kb  = (u16*)p; p += NM * 2;
  u16* Vb  = (u16*)p; p += NM * 2;
  u16* Vtb = (u16*)p; p += NM * 2;
  u16* AOb = (u16*)p; p += NM * 2;
  u16* Wqb = (u16*)p; p += WW * 2;
  u16* Wkb = (u16*)p; p += WW * 2;
  u16* Wvb = (u16*)p; p += WW * 2;
  u16* Wob = (u16*)p; p += WW * 2;
  size_t base = (size_t)(p - (char*)d_ws);

  // chunked: per chunk need S (bf16) + S2 (fp32) of CQ x 16 x 2048
  int CQ = 0;
  const int cands[6] = {2048, 1024, 512, 256, 128, 64};
  for (int i = 0; i < 6; ++i) {
    size_t need = base + (size_t)cands[i] * NHEAD * N_TOK * (2 + 4);
    if (need <= ws_size) { CQ = cands[i]; break; }
  }
  if (CQ == 0) return;
  u16* S    = (u16*)p;
  float* S2 = (float*)(p + (size_t)CQ * NHEAD * N_TOK * 2);

  ln_kernel<<<N_TOK / 4, 256, 0, stream>>>(x, gamma, beta, xnb);
  cast_kernel<<<512, 256, 0, stream>>>(Wq, Wqb, WW / 8);
  cast_kernel<<<512, 256, 0, stream>>>(Wk, Wkb, WW / 8);
  cast_kernel<<<512, 256, 0, stream>>>(Wv, Wvb, WW / 8);
  cast_kernel<<<512, 256, 0, stream>>>(Wo, Wob, WW / 8);

  gemm_bf16_nt<<<dim3(16, 32, 1), 256, 0, stream>>>(xnb, DMODEL, 0, Wqb, DMODEL, 0,
                                                    Qb, DMODEL, 0, DMODEL, 1.f, bq, nullptr, 0);
  gemm_bf16_nt<<<dim3(16, 32, 1), 256, 0, stream>>>(xnb, DMODEL, 0, Wkb, DMODEL, 0,
                                                    Kb, DMODEL, 0, DMODEL, 1.f, bk, nullptr, 0);
  gemm_bf16_nt<<<dim3(16, 32, 1), 256, 0, stream>>>(xnb, DMODEL, 0, Wvb, DMODEL, 0,
                                                    Vb, DMODEL, 0, DMODEL, 1.f, bv, nullptr, 0);
  transpose_kernel<<<dim3(N_TOK / 64, DMODEL / 64), 256, 0, stream>>>(Vb, Vtb);

  for (int q0 = 0; q0 < N_TOK; q0 += CQ) {
    // scores: S[ql][h][k] = 0.125 * Q_h[q0+ql] . K_h^T   (bf16 out)
    gemm_bf16_nt<<<dim3(N_TOK / 64, CQ / 64, NHEAD), 256, 0, stream>>>(
        Qb + (size_t)q0 * DMODEL, DMODEL, HDK, Kb, DMODEL, HDK,
        S, NHEAD * N_TOK, N_TOK, HDK, 0.125f, nullptr, nullptr, 0);

    // M1: premix  S2[g] = Wpre . S[h]   (fp32 out, exact topk domain)
    headmix_kernel<<<dim3(CQ, 4), 256, 0, stream>>>(S, Wpre, nullptr, S2, 1);

    // M2: per-row softmax + exact top-128 + renorm  -> attn (bf16) into S
    topk_rows_kernel<<<CQ * NHEAD / 4, 256, 0, stream>>>(S2, S);

    // M3: postmix  attn2[g] = Wpost . attn[h] + bpost  (bf16, in place)
    headmix_kernel<<<dim3(CQ, 4), 256, 0, stream>>>(S, Wpost, bpost, S, 0);

    // PV: AO[q0+ql][h*64+d] = attn2[ql][h][:] . Vt_h[d][:]   (bf16 out)
    gemm_bf16_nt<<<dim3(1, CQ / 64, NHEAD), 256, 0, stream>>>(
        S, NHEAD * N_TOK, N_TOK, Vtb, N_TOK, HDK * N_TOK,
        AOb + (size_t)q0 * DMODEL, DMODEL, HDK, N_TOK, 1.f, nullptr, nullptr, 0);
  }

  // out = AO @ Wo^T + bo + x   (fp32 out)
  gemm_bf16_nt<<<dim3(16, 32, 1), 256, 0, stream>>>(AOb, DMODEL, 0, Wob, DMODEL, 0,
                                                    d_out, DMODEL, 0, DMODEL, 1.f, bo, x, 1);
}

// Round 8
// 568.926 us; speedup vs baseline: 4.0381x; 1.0206x over previous
//
#include <hip/hip_runtime.h>
#include <stdint.h>

typedef unsigned short u16;
using bf16x8 = __attribute__((ext_vector_type(8))) short;
using f32x4  = __attribute__((ext_vector_type(4))) float;

#define N_TOK 2048
#define DMODEL 1024
#define NHEAD 16
#define HDK 64
#define TOPK_K 128

// ---------------- numeric helpers ----------------
__device__ __forceinline__ u16 f2b(float f) {  // fp32 -> bf16 RNE
  unsigned u = __float_as_uint(f);
  return (u16)((u + 0x7FFFu + ((u >> 16) & 1u)) >> 16);
}
__device__ __forceinline__ float b2f(u16 b) {
  return __uint_as_float(((unsigned)b) << 16);
}
__device__ __forceinline__ float wave_reduce_sum(float v) {
#pragma unroll
  for (int d = 32; d >= 1; d >>= 1) v += __shfl_xor(v, d);
  return v;
}
// order-preserving fp32-bits -> uint key (ascending float -> ascending uint)
__device__ __forceinline__ unsigned bits2key(unsigned u) {
  return (u & 0x80000000u) ? ~u : (u | 0x80000000u);
}
__device__ __forceinline__ float key2f(unsigned k) {
  unsigned u = (k & 0x80000000u) ? (k ^ 0x80000000u) : ~k;
  return __uint_as_float(u);
}

// ---------------- LayerNorm -> bf16 ----------------
__global__ __launch_bounds__(256) void ln_kernel(const float* __restrict__ x,
                                                 const float* __restrict__ gamma,
                                                 const float* __restrict__ beta,
                                                 u16* __restrict__ xn) {
  int w = threadIdx.x >> 6, lane = threadIdx.x & 63;
  int row = blockIdx.x * 4 + w;
  const float4* xr = (const float4*)(x + (size_t)row * DMODEL);
  float4 v[4];
  float s = 0.f, ss = 0.f;
#pragma unroll
  for (int i = 0; i < 4; ++i) {
    v[i] = xr[i * 64 + lane];
    s += v[i].x + v[i].y + v[i].z + v[i].w;
    ss += v[i].x * v[i].x + v[i].y * v[i].y + v[i].z * v[i].z + v[i].w * v[i].w;
  }
  s = wave_reduce_sum(s);
  ss = wave_reduce_sum(ss);
  float mu = s * (1.f / DMODEL);
  float var = ss * (1.f / DMODEL) - mu * mu;
  float rstd = rsqrtf(var + 1e-5f);
  const float4* g4 = (const float4*)gamma;
  const float4* b4 = (const float4*)beta;
  u16* xo = xn + (size_t)row * DMODEL;
#pragma unroll
  for (int i = 0; i < 4; ++i) {
    float4 g = g4[i * 64 + lane], b = b4[i * 64 + lane];
    float ox = (v[i].x - mu) * rstd * g.x + b.x;
    float oy = (v[i].y - mu) * rstd * g.y + b.y;
    float oz = (v[i].z - mu) * rstd * g.z + b.z;
    float ow = (v[i].w - mu) * rstd * g.w + b.w;
    unsigned lo = (unsigned)f2b(ox) | ((unsigned)f2b(oy) << 16);
    unsigned hi = (unsigned)f2b(oz) | ((unsigned)f2b(ow) << 16);
    *(uint2*)&xo[(i * 64 + lane) * 4] = make_uint2(lo, hi);
  }
}

// ---------------- fp32 -> bf16 cast (n8 = elems/8) ----------------
__global__ __launch_bounds__(256) void cast_kernel(const float* __restrict__ in,
                                                   u16* __restrict__ out, int n8) {
  int i = blockIdx.x * 256 + threadIdx.x;
  if (i >= n8) return;
  const float4* p = (const float4*)in + (size_t)i * 2;
  float4 a = p[0], b = p[1];
  unsigned w0 = (unsigned)f2b(a.x) | ((unsigned)f2b(a.y) << 16);
  unsigned w1 = (unsigned)f2b(a.z) | ((unsigned)f2b(a.w) << 16);
  unsigned w2 = (unsigned)f2b(b.x) | ((unsigned)f2b(b.y) << 16);
  unsigned w3 = (unsigned)f2b(b.z) | ((unsigned)f2b(b.w) << 16);
  *(uint4*)&out[(size_t)i * 8] = make_uint4(w0, w1, w2, w3);
}

// ---------------- concat 3 fp32 vectors (1024 each) ----------------
__global__ __launch_bounds__(256) void concat3_kernel(const float* __restrict__ a,
                                                      const float* __restrict__ b,
                                                      const float* __restrict__ c,
                                                      float* __restrict__ out) {
  int i = blockIdx.x * 256 + threadIdx.x;
  if (i < 1024) out[i] = a[i];
  else if (i < 2048) out[i] = b[i - 1024];
  else if (i < 3072) out[i] = c[i - 2048];
}

// ---------------- bf16 transpose with input ld (V view -> Vt 1024x2048) ----------
__global__ __launch_bounds__(256) void transpose_kernel(const u16* __restrict__ V, int ldv,
                                                        u16* __restrict__ Vt) {
  __shared__ u16 tile[64][72];
  int kb = blockIdx.x * 64, cb = blockIdx.y * 64;
  int t = threadIdx.x;
  int r = t >> 2, cg = (t & 3) * 16;
  *(uint4*)&tile[r][cg]     = *(const uint4*)&V[(size_t)(kb + r) * ldv + cb + cg];
  *(uint4*)&tile[r][cg + 8] = *(const uint4*)&V[(size_t)(kb + r) * ldv + cb + cg + 8];
  __syncthreads();
  int c = t >> 2, kg = (t & 3) * 16;
  size_t base = (size_t)(cb + c) * N_TOK + kb + kg;
  unsigned p0 = (unsigned)tile[kg + 0][c] | ((unsigned)tile[kg + 1][c] << 16);
  unsigned p1 = (unsigned)tile[kg + 2][c] | ((unsigned)tile[kg + 3][c] << 16);
  unsigned p2 = (unsigned)tile[kg + 4][c] | ((unsigned)tile[kg + 5][c] << 16);
  unsigned p3 = (unsigned)tile[kg + 6][c] | ((unsigned)tile[kg + 7][c] << 16);
  unsigned p4 = (unsigned)tile[kg + 8][c] | ((unsigned)tile[kg + 9][c] << 16);
  unsigned p5 = (unsigned)tile[kg + 10][c] | ((unsigned)tile[kg + 11][c] << 16);
  unsigned p6 = (unsigned)tile[kg + 12][c] | ((unsigned)tile[kg + 13][c] << 16);
  unsigned p7 = (unsigned)tile[kg + 14][c] | ((unsigned)tile[kg + 15][c] << 16);
  *(uint4*)&Vt[base]     = make_uint4(p0, p1, p2, p3);
  *(uint4*)&Vt[base + 8] = make_uint4(p4, p5, p6, p7);
}

// ---------------- bf16 MFMA GEMM: C = scale*(A . B^T) [+bias] [+res] ----------------
__global__ __launch_bounds__(256) void gemm_bf16_nt(
    const u16* __restrict__ A, int lda, int az,
    const u16* __restrict__ B, int ldb, int bz,
    void* __restrict__ Cv, int ldc, int cz,
    int K, float scale,
    const float* __restrict__ bias,
    const float* __restrict__ res, int out_f32) {
  __shared__ u16 As[64 * 40];  // row stride 40 bf16 (80 B): 16B-aligned, 2-way max
  __shared__ u16 Bs[64 * 40];
  A += (size_t)blockIdx.z * az;
  B += (size_t)blockIdx.z * bz;
  int bi = blockIdx.y * 64, bj = blockIdx.x * 64;
  int tid = threadIdx.x;
  int w = tid >> 6, lane = tid & 63;
  int wr = w >> 1, wc = w & 1;
  int lr = tid >> 2, lc = (tid & 3) * 8;
  int kh = (lane >> 4) * 8, fr = lane & 15;
  f32x4 acc[2][2] = {};
  for (int k0 = 0; k0 < K; k0 += 32) {
    *(uint4*)&As[lr * 40 + lc] = *(const uint4*)&A[(size_t)(bi + lr) * lda + k0 + lc];
    *(uint4*)&Bs[lr * 40 + lc] = *(const uint4*)&B[(size_t)(bj + lr) * ldb + k0 + lc];
    __syncthreads();
    bf16x8 a0 = *(bf16x8*)&As[(wr * 32 + fr) * 40 + kh];
    bf16x8 a1 = *(bf16x8*)&As[(wr * 32 + 16 + fr) * 40 + kh];
    bf16x8 b0 = *(bf16x8*)&Bs[(wc * 32 + fr) * 40 + kh];
    bf16x8 b1 = *(bf16x8*)&Bs[(wc * 32 + 16 + fr) * 40 + kh];
    acc[0][0] = __builtin_amdgcn_mfma_f32_16x16x32_bf16(a0, b0, acc[0][0], 0, 0, 0);
    acc[0][1] = __builtin_amdgcn_mfma_f32_16x16x32_bf16(a0, b1, acc[0][1], 0, 0, 0);
    acc[1][0] = __builtin_amdgcn_mfma_f32_16x16x32_bf16(a1, b0, acc[1][0], 0, 0, 0);
    acc[1][1] = __builtin_amdgcn_mfma_f32_16x16x32_bf16(a1, b1, acc[1][1], 0, 0, 0);
    __syncthreads();
  }
  float* Cf = (float*)Cv + (size_t)blockIdx.z * cz;
  u16* Ch = (u16*)Cv + (size_t)blockIdx.z * cz;
  int rg = (lane >> 4) * 4;
#pragma unroll
  for (int m = 0; m < 2; ++m) {
#pragma unroll
    for (int n = 0; n < 2; ++n) {
      int gcol = bj + wc * 32 + n * 16 + fr;
      float badd = bias ? bias[gcol] : 0.f;
#pragma unroll
      for (int r = 0; r < 4; ++r) {
        int grow = bi + wr * 32 + m * 16 + rg + r;
        size_t off = (size_t)grow * ldc + gcol;
        float v = acc[m][n][r] * scale + badd;
        if (res) v += res[off];
        if (out_f32) Cf[off] = v;
        else Ch[off] = f2b(v);
      }
    }
  }
}

// ---------------- M1/M3: head-mix per (q,k) column: out[g] = W[g,:] . in[:] (+bias) ----
__global__ __launch_bounds__(256) void headmix_kernel(
    const u16* __restrict__ in, const float* __restrict__ W,
    const float* __restrict__ bias, void* __restrict__ out, int out_f32) {
  __shared__ u16 tile[NHEAD][512];
  __shared__ float w_s[256];
  __shared__ float b_s[16];
  int q = blockIdx.x, kb = blockIdx.y * 512;
  int t = threadIdx.x;
  w_s[t] = W[t];
  if (t < 16) b_s[t] = bias ? bias[t] : 0.f;
#pragma unroll
  for (int j = 0; j < 4; ++j) {
    int idx = j * 256 + t;
    int h = idx >> 6, cu = idx & 63;
    ((uint4*)&tile[h][0])[cu] =
        ((const uint4*)(in + ((size_t)q * NHEAD + h) * N_TOK + kb))[cu];
  }
  __syncthreads();
  float sv0[16], sv1[16];
#pragma unroll
  for (int h = 0; h < 16; ++h) {
    unsigned pw = ((const unsigned*)&tile[h][0])[t];
    sv0[h] = b2f((u16)(pw & 0xFFFFu));
    sv1[h] = b2f((u16)(pw >> 16));
  }
#pragma unroll
  for (int g = 0; g < 16; ++g) {
    float a0 = b_s[g], a1 = b_s[g];
#pragma unroll
    for (int h = 0; h < 16; ++h) {
      float wv = w_s[g * 16 + h];
      a0 = fmaf(wv, sv0[h], a0);
      a1 = fmaf(wv, sv1[h], a1);
    }
    size_t obase = ((size_t)q * NHEAD + g) * N_TOK + kb;
    if (out_f32) {
      ((float2*)((float*)out + obase))[t] = make_float2(a0, a1);
    } else {
      ((unsigned*)((u16*)out + obase))[t] =
          (unsigned)f2b(a0) | ((unsigned)f2b(a1) << 16);
    }
  }
}

// ---------------- M2: per-row softmax + exact top-128 + renorm ----------------
// One WAVE per (q,g) row. Count via ballot+popcll (wave-uniform in SGPR, SALU
// parallel to VALU); keys + exps cached in registers (static indices only).
__global__ __launch_bounds__(256, 4) void topk_rows_kernel(
    const float* __restrict__ S2, u16* __restrict__ S) {
  int row = blockIdx.x * 4 + (threadIdx.x >> 6);
  int lane = threadIdx.x & 63;
  const uint4* rp = (const uint4*)(S2 + (size_t)row * N_TOK);
  unsigned key[32];
#pragma unroll
  for (int i = 0; i < 8; ++i) {
    uint4 u = rp[i * 64 + lane];
    key[i * 4 + 0] = bits2key(u.x);
    key[i * 4 + 1] = bits2key(u.y);
    key[i * 4 + 2] = bits2key(u.z);
    key[i * 4 + 3] = bits2key(u.w);
  }
  // row max (keys order-preserving)
  unsigned kmax = 0u;
#pragma unroll
  for (int j = 0; j < 32; ++j) kmax = key[j] > kmax ? key[j] : kmax;
#pragma unroll
  for (int d = 32; d >= 1; d >>= 1) {
    unsigned o = (unsigned)__shfl_xor((int)kmax, d);
    kmax = o > kmax ? o : kmax;
  }
  float mx = key2f(kmax);
  // exact 128th-largest key: 32-step binary search, ballot+popcount counting
  unsigned T = 0u;
#pragma unroll 1
  for (int bit = 31; bit >= 0; --bit) {
    unsigned cand = T | (1u << bit);
    int c = 0;
#pragma unroll
    for (int j = 0; j < 32; ++j)
      c += (int)__popcll(__ballot(key[j] >= cand));
    if (c >= TOPK_K) T = cand;
  }
  // single exp pass; e[] cached for writeback
  float e[32];
  float z = 0.f, ms = 0.f;
#pragma unroll
  for (int j = 0; j < 32; ++j) {
    float ev = __expf(key2f(key[j]) - mx);
    e[j] = ev;
    z += ev;
    if (key[j] >= T) ms += ev;
  }
  z = wave_reduce_sum(z);
  ms = wave_reduce_sum(ms);
  // out = (e/z) / (ms/z + 1e-9) = e / (ms + 1e-9*z); ties (key==T) kept
  float cs = 1.f / (ms + 1e-9f * z);
  u16* op = S + (size_t)row * N_TOK;
#pragma unroll
  for (int i = 0; i < 8; ++i) {
    unsigned pk[4];
#pragma unroll
    for (int c2 = 0; c2 < 4; ++c2) {
      unsigned k = key[i * 4 + c2];
      float val = (k >= T) ? e[i * 4 + c2] * cs : 0.f;
      pk[c2] = (unsigned)f2b(val);
    }
    uint2 w2;
    w2.x = pk[0] | (pk[1] << 16);
    w2.y = pk[2] | (pk[3] << 16);
    ((uint2*)op)[i * 64 + lane] = w2;
  }
}

// ---------------- launch ----------------
extern "C" void kernel_launch(void* const* d_in, const int* in_sizes, int n_in,
                              void* d_out, int out_size, void* d_ws, size_t ws_size,
                              hipStream_t stream) {
  const float* x     = (const float*)d_in[0];
  const float* Wq    = (const float*)d_in[1];
  const float* bq    = (const float*)d_in[2];
  const float* Wk    = (const float*)d_in[3];
  const float* bk    = (const float*)d_in[4];
  const float* Wv    = (const float*)d_in[5];
  const float* bv    = (const float*)d_in[6];
  const float* Wpre  = (const float*)d_in[7];
  // d_in[8] = bpre: no-op (softmax shift-invariant; top-k order unchanged)
  const float* Wpost = (const float*)d_in[9];
  const float* bpost = (const float*)d_in[10];
  const float* Wo    = (const float*)d_in[11];
  const float* bo    = (const float*)d_in[12];
  const float* gamma = (const float*)d_in[13];
  const float* beta  = (const float*)d_in[14];

  const size_t NM = (size_t)N_TOK * DMODEL;   // 2M elems
  const size_t WW = (size_t)DMODEL * DMODEL;  // 1M elems
  const int D3 = 3 * DMODEL;                  // 3072
  char* p = (char*)d_ws;
  u16* xnb   = (u16*)p; p += NM * 2;
  u16* QKVb  = (u16*)p; p += (size_t)N_TOK * D3 * 2;  // fused Q|K|V, row stride 3072
  u16* Vtb   = (u16*)p; p += NM * 2;
  u16* AOb   = (u16*)p; p += NM * 2;
  u16* WQKVb = (u16*)p; p += 3 * WW * 2;              // [Wq;Wk;Wv] rows
  u16* Wob   = (u16*)p; p += WW * 2;
  float* bqkv = (float*)p; p += D3 * 4;
  size_t base = (size_t)(p - (char*)d_ws);

  // chunked: per chunk need S (bf16) + S2 (fp32) of CQ x 16 x 2048
  int CQ = 0;
  const int cands[6] = {2048, 1024, 512, 256, 128, 64};
  for (int i = 0; i < 6; ++i) {
    size_t need = base + (size_t)cands[i] * NHEAD * N_TOK * (2 + 4);
    if (need <= ws_size) { CQ = cands[i]; break; }
  }
  if (CQ == 0) return;
  u16* S    = (u16*)p;
  float* S2 = (float*)(p + (size_t)CQ * NHEAD * N_TOK * 2);

  ln_kernel<<<N_TOK / 4, 256, 0, stream>>>(x, gamma, beta, xnb);
  cast_kernel<<<512, 256, 0, stream>>>(Wq, WQKVb, WW / 8);
  cast_kernel<<<512, 256, 0, stream>>>(Wk, WQKVb + WW, WW / 8);
  cast_kernel<<<512, 256, 0, stream>>>(Wv, WQKVb + 2 * WW, WW / 8);
  cast_kernel<<<512, 256, 0, stream>>>(Wo, Wob, WW / 8);
  concat3_kernel<<<12, 256, 0, stream>>>(bq, bk, bv, bqkv);

  // fused QKV projection: QKV = xn @ [Wq;Wk;Wv]^T + [bq;bk;bv]  (bf16, ld 3072)
  gemm_bf16_nt<<<dim3(48, 32, 1), 256, 0, stream>>>(xnb, DMODEL, 0, WQKVb, DMODEL, 0,
                                                    QKVb, D3, 0, DMODEL, 1.f, bqkv, nullptr, 0);
  // Vt from V view (cols 2048.., ld 3072)
  transpose_kernel<<<dim3(N_TOK / 64, DMODEL / 64), 256, 0, stream>>>(QKVb + 2048, D3, Vtb);

  for (int q0 = 0; q0 < N_TOK; q0 += CQ) {
    // scores: S[ql][h][k] = 0.125 * Q_h[q0+ql] . K_h^T   (bf16 out)
    gemm_bf16_nt<<<dim3(N_TOK / 64, CQ / 64, NHEAD), 256, 0, stream>>>(
        QKVb + (size_t)q0 * D3, D3, HDK, QKVb + 1024, D3, HDK,
        S, NHEAD * N_TOK, N_TOK, HDK, 0.125f, nullptr, nullptr, 0);

    // M1: premix  S2[g] = Wpre . S[h]   (fp32 out, exact topk domain)
    headmix_kernel<<<dim3(CQ, 4), 256, 0, stream>>>(S, Wpre, nullptr, S2, 1);

    // M2: per-row softmax + exact top-128 + renorm  -> attn (bf16) into S
    topk_rows_kernel<<<CQ * NHEAD / 4, 256, 0, stream>>>(S2, S);

    // M3: postmix  attn2[g] = Wpost . attn[h] + bpost  (bf16, in place)
    headmix_kernel<<<dim3(CQ, 4), 256, 0, stream>>>(S, Wpost, bpost, S, 0);

    // PV: AO[q0+ql][h*64+d] = attn2[ql][h][:] . Vt_h[d][:]   (bf16 out)
    gemm_bf16_nt<<<dim3(1, CQ / 64, NHEAD), 256, 0, stream>>>(
        S, NHEAD * N_TOK, N_TOK, Vtb, N_TOK, HDK * N_TOK,
        AOb + (size_t)q0 * DMODEL, DMODEL, HDK, N_TOK, 1.f, nullptr, nullptr, 0);
  }

  // out = AO @ Wo^T + bo + x   (fp32 out)
  gemm_bf16_nt<<<dim3(16, 32, 1), 256, 0, stream>>>(AOb, DMODEL, 0, Wob, DMODEL, 0,
                                                    d_out, DMODEL, 0, DMODEL, 1.f, bo, x, 1);
}

// Round 9
// 486.762 us; speedup vs baseline: 4.7197x; 1.1688x over previous
//
#include <hip/hip_runtime.h>
#include <stdint.h>

typedef unsigned short u16;
using bf16x8 = __attribute__((ext_vector_type(8))) short;
using f32x4  = __attribute__((ext_vector_type(4))) float;

#define N_TOK 2048
#define DMODEL 1024
#define NHEAD 16
#define HDK 64
#define TOPK_K 128

// ---------------- numeric helpers ----------------
__device__ __forceinline__ u16 f2b(float f) {  // fp32 -> bf16 RNE
  unsigned u = __float_as_uint(f);
  return (u16)((u + 0x7FFFu + ((u >> 16) & 1u)) >> 16);
}
__device__ __forceinline__ float b2f(u16 b) {
  return __uint_as_float(((unsigned)b) << 16);
}
__device__ __forceinline__ float wave_reduce_sum(float v) {
#pragma unroll
  for (int d = 32; d >= 1; d >>= 1) v += __shfl_xor(v, d);
  return v;
}
// order-preserving fp32-bits -> uint key (ascending float -> ascending uint)
__device__ __forceinline__ unsigned bits2key(unsigned u) {
  return (u & 0x80000000u) ? ~u : (u | 0x80000000u);
}
__device__ __forceinline__ float key2f(unsigned k) {
  unsigned u = (k & 0x80000000u) ? (k ^ 0x80000000u) : ~k;
  return __uint_as_float(u);
}

// ---------------- LayerNorm -> bf16 ----------------
__global__ __launch_bounds__(256) void ln_kernel(const float* __restrict__ x,
                                                 const float* __restrict__ gamma,
                                                 const float* __restrict__ beta,
                                                 u16* __restrict__ xn) {
  int w = threadIdx.x >> 6, lane = threadIdx.x & 63;
  int row = blockIdx.x * 4 + w;
  const float4* xr = (const float4*)(x + (size_t)row * DMODEL);
  float4 v[4];
  float s = 0.f, ss = 0.f;
#pragma unroll
  for (int i = 0; i < 4; ++i) {
    v[i] = xr[i * 64 + lane];
    s += v[i].x + v[i].y + v[i].z + v[i].w;
    ss += v[i].x * v[i].x + v[i].y * v[i].y + v[i].z * v[i].z + v[i].w * v[i].w;
  }
  s = wave_reduce_sum(s);
  ss = wave_reduce_sum(ss);
  float mu = s * (1.f / DMODEL);
  float var = ss * (1.f / DMODEL) - mu * mu;
  float rstd = rsqrtf(var + 1e-5f);
  const float4* g4 = (const float4*)gamma;
  const float4* b4 = (const float4*)beta;
  u16* xo = xn + (size_t)row * DMODEL;
#pragma unroll
  for (int i = 0; i < 4; ++i) {
    float4 g = g4[i * 64 + lane], b = b4[i * 64 + lane];
    float ox = (v[i].x - mu) * rstd * g.x + b.x;
    float oy = (v[i].y - mu) * rstd * g.y + b.y;
    float oz = (v[i].z - mu) * rstd * g.z + b.z;
    float ow = (v[i].w - mu) * rstd * g.w + b.w;
    unsigned lo = (unsigned)f2b(ox) | ((unsigned)f2b(oy) << 16);
    unsigned hi = (unsigned)f2b(oz) | ((unsigned)f2b(ow) << 16);
    *(uint2*)&xo[(i * 64 + lane) * 4] = make_uint2(lo, hi);
  }
}

// ---------------- fp32 -> bf16 cast (n8 = elems/8) ----------------
__global__ __launch_bounds__(256) void cast_kernel(const float* __restrict__ in,
                                                   u16* __restrict__ out, int n8) {
  int i = blockIdx.x * 256 + threadIdx.x;
  if (i >= n8) return;
  const float4* p = (const float4*)in + (size_t)i * 2;
  float4 a = p[0], b = p[1];
  unsigned w0 = (unsigned)f2b(a.x) | ((unsigned)f2b(a.y) << 16);
  unsigned w1 = (unsigned)f2b(a.z) | ((unsigned)f2b(a.w) << 16);
  unsigned w2 = (unsigned)f2b(b.x) | ((unsigned)f2b(b.y) << 16);
  unsigned w3 = (unsigned)f2b(b.z) | ((unsigned)f2b(b.w) << 16);
  *(uint4*)&out[(size_t)i * 8] = make_uint4(w0, w1, w2, w3);
}

// ---------------- concat 3 fp32 vectors (1024 each) ----------------
__global__ __launch_bounds__(256) void concat3_kernel(const float* __restrict__ a,
                                                      const float* __restrict__ b,
                                                      const float* __restrict__ c,
                                                      float* __restrict__ out) {
  int i = blockIdx.x * 256 + threadIdx.x;
  if (i < 1024) out[i] = a[i];
  else if (i < 2048) out[i] = b[i - 1024];
  else if (i < 3072) out[i] = c[i - 2048];
}

// ---------------- bf16 transpose with input ld (V view -> Vt 1024x2048) ----------
__global__ __launch_bounds__(256) void transpose_kernel(const u16* __restrict__ V, int ldv,
                                                        u16* __restrict__ Vt) {
  __shared__ u16 tile[64][72];
  int kb = blockIdx.x * 64, cb = blockIdx.y * 64;
  int t = threadIdx.x;
  int r = t >> 2, cg = (t & 3) * 16;
  *(uint4*)&tile[r][cg]     = *(const uint4*)&V[(size_t)(kb + r) * ldv + cb + cg];
  *(uint4*)&tile[r][cg + 8] = *(const uint4*)&V[(size_t)(kb + r) * ldv + cb + cg + 8];
  __syncthreads();
  int c = t >> 2, kg = (t & 3) * 16;
  size_t base = (size_t)(cb + c) * N_TOK + kb + kg;
  unsigned p0 = (unsigned)tile[kg + 0][c] | ((unsigned)tile[kg + 1][c] << 16);
  unsigned p1 = (unsigned)tile[kg + 2][c] | ((unsigned)tile[kg + 3][c] << 16);
  unsigned p2 = (unsigned)tile[kg + 4][c] | ((unsigned)tile[kg + 5][c] << 16);
  unsigned p3 = (unsigned)tile[kg + 6][c] | ((unsigned)tile[kg + 7][c] << 16);
  unsigned p4 = (unsigned)tile[kg + 8][c] | ((unsigned)tile[kg + 9][c] << 16);
  unsigned p5 = (unsigned)tile[kg + 10][c] | ((unsigned)tile[kg + 11][c] << 16);
  unsigned p6 = (unsigned)tile[kg + 12][c] | ((unsigned)tile[kg + 13][c] << 16);
  unsigned p7 = (unsigned)tile[kg + 14][c] | ((unsigned)tile[kg + 15][c] << 16);
  *(uint4*)&Vt[base]     = make_uint4(p0, p1, p2, p3);
  *(uint4*)&Vt[base + 8] = make_uint4(p4, p5, p6, p7);
}

// ---------------- bf16 MFMA GEMM: C = scale*(A . B^T) [+bias] [+res] ----------------
__global__ __launch_bounds__(256) void gemm_bf16_nt(
    const u16* __restrict__ A, int lda, int az,
    const u16* __restrict__ B, int ldb, int bz,
    void* __restrict__ Cv, int ldc, int cz,
    int K, float scale,
    const float* __restrict__ bias,
    const float* __restrict__ res, int out_f32) {
  __shared__ u16 As[64 * 40];  // row stride 40 bf16 (80 B): 16B-aligned, 2-way max
  __shared__ u16 Bs[64 * 40];
  A += (size_t)blockIdx.z * az;
  B += (size_t)blockIdx.z * bz;
  int bi = blockIdx.y * 64, bj = blockIdx.x * 64;
  int tid = threadIdx.x;
  int w = tid >> 6, lane = tid & 63;
  int wr = w >> 1, wc = w & 1;
  int lr = tid >> 2, lc = (tid & 3) * 8;
  int kh = (lane >> 4) * 8, fr = lane & 15;
  f32x4 acc[2][2] = {};
  for (int k0 = 0; k0 < K; k0 += 32) {
    *(uint4*)&As[lr * 40 + lc] = *(const uint4*)&A[(size_t)(bi + lr) * lda + k0 + lc];
    *(uint4*)&Bs[lr * 40 + lc] = *(const uint4*)&B[(size_t)(bj + lr) * ldb + k0 + lc];
    __syncthreads();
    bf16x8 a0 = *(bf16x8*)&As[(wr * 32 + fr) * 40 + kh];
    bf16x8 a1 = *(bf16x8*)&As[(wr * 32 + 16 + fr) * 40 + kh];
    bf16x8 b0 = *(bf16x8*)&Bs[(wc * 32 + fr) * 40 + kh];
    bf16x8 b1 = *(bf16x8*)&Bs[(wc * 32 + 16 + fr) * 40 + kh];
    acc[0][0] = __builtin_amdgcn_mfma_f32_16x16x32_bf16(a0, b0, acc[0][0], 0, 0, 0);
    acc[0][1] = __builtin_amdgcn_mfma_f32_16x16x32_bf16(a0, b1, acc[0][1], 0, 0, 0);
    acc[1][0] = __builtin_amdgcn_mfma_f32_16x16x32_bf16(a1, b0, acc[1][0], 0, 0, 0);
    acc[1][1] = __builtin_amdgcn_mfma_f32_16x16x32_bf16(a1, b1, acc[1][1], 0, 0, 0);
    __syncthreads();
  }
  float* Cf = (float*)Cv + (size_t)blockIdx.z * cz;
  u16* Ch = (u16*)Cv + (size_t)blockIdx.z * cz;
  int rg = (lane >> 4) * 4;
#pragma unroll
  for (int m = 0; m < 2; ++m) {
#pragma unroll
    for (int n = 0; n < 2; ++n) {
      int gcol = bj + wc * 32 + n * 16 + fr;
      float badd = bias ? bias[gcol] : 0.f;
#pragma unroll
      for (int r = 0; r < 4; ++r) {
        int grow = bi + wr * 32 + m * 16 + rg + r;
        size_t off = (size_t)grow * ldc + gcol;
        float v = acc[m][n][r] * scale + badd;
        if (res) v += res[off];
        if (out_f32) Cf[off] = v;
        else Ch[off] = f2b(v);
      }
    }
  }
}

// ---------------- M3: head-mix per (q,k) column: out[g] = W[g,:] . in[:] (+bias) ----
__global__ __launch_bounds__(256) void headmix_kernel(
    const u16* __restrict__ in, const float* __restrict__ W,
    const float* __restrict__ bias, void* __restrict__ out, int out_f32) {
  __shared__ u16 tile[NHEAD][512];
  __shared__ float w_s[256];
  __shared__ float b_s[16];
  int q = blockIdx.x, kb = blockIdx.y * 512;
  int t = threadIdx.x;
  w_s[t] = W[t];
  if (t < 16) b_s[t] = bias ? bias[t] : 0.f;
#pragma unroll
  for (int j = 0; j < 4; ++j) {
    int idx = j * 256 + t;
    int h = idx >> 6, cu = idx & 63;
    ((uint4*)&tile[h][0])[cu] =
        ((const uint4*)(in + ((size_t)q * NHEAD + h) * N_TOK + kb))[cu];
  }
  __syncthreads();
  float sv0[16], sv1[16];
#pragma unroll
  for (int h = 0; h < 16; ++h) {
    unsigned pw = ((const unsigned*)&tile[h][0])[t];
    sv0[h] = b2f((u16)(pw & 0xFFFFu));
    sv1[h] = b2f((u16)(pw >> 16));
  }
#pragma unroll
  for (int g = 0; g < 16; ++g) {
    float a0 = b_s[g], a1 = b_s[g];
#pragma unroll
    for (int h = 0; h < 16; ++h) {
      float wv = w_s[g * 16 + h];
      a0 = fmaf(wv, sv0[h], a0);
      a1 = fmaf(wv, sv1[h], a1);
    }
    size_t obase = ((size_t)q * NHEAD + g) * N_TOK + kb;
    if (out_f32) {
      ((float2*)((float*)out + obase))[t] = make_float2(a0, a1);
    } else {
      ((unsigned*)((u16*)out + obase))[t] =
          (unsigned)f2b(a0) | ((unsigned)f2b(a1) << 16);
    }
  }
}

// ---------------- fused premix + softmax + exact top-128 + renorm ----------------
// One WAVE per (q,g) row; 4 waves/block = g0..g0+3 of the SAME q (slab L2 reuse).
// Premix streamed from bf16 scores (h-sequential fmaf, fp32 — bit-identical to the
// old M1). 32 accumulators/keys held in NAMED float4/uint4 fields so the compiler
// cannot demote them to memory. Binary-search threshold with ballot counting and
// exact early exit (count==128 <=> mask identical to reference attn>=kth).
#define ACCS_APPLY(OP) \
  OP(0, A0.x, A0.y)  OP(1, A0.z, A0.w)  OP(2, A1.x, A1.y)  OP(3, A1.z, A1.w) \
  OP(4, A2.x, A2.y)  OP(5, A2.z, A2.w)  OP(6, A3.x, A3.y)  OP(7, A3.z, A3.w) \
  OP(8, A4.x, A4.y)  OP(9, A4.z, A4.w)  OP(10, A5.x, A5.y) OP(11, A5.z, A5.w) \
  OP(12, A6.x, A6.y) OP(13, A6.z, A6.w) OP(14, A7.x, A7.y) OP(15, A7.z, A7.w)
#define KEYS_APPLY(OP) \
  OP(Q0.x) OP(Q0.y) OP(Q0.z) OP(Q0.w) OP(Q1.x) OP(Q1.y) OP(Q1.z) OP(Q1.w) \
  OP(Q2.x) OP(Q2.y) OP(Q2.z) OP(Q2.w) OP(Q3.x) OP(Q3.y) OP(Q3.z) OP(Q3.w) \
  OP(Q4.x) OP(Q4.y) OP(Q4.z) OP(Q4.w) OP(Q5.x) OP(Q5.y) OP(Q5.z) OP(Q5.w) \
  OP(Q6.x) OP(Q6.y) OP(Q6.z) OP(Q6.w) OP(Q7.x) OP(Q7.y) OP(Q7.z) OP(Q7.w)

__global__ __launch_bounds__(256, 4) void premix_topk_kernel(
    const u16* __restrict__ Sin, const float* __restrict__ Wpre,
    u16* __restrict__ Sout) {
  int bid = blockIdx.x;
  int q = bid >> 2;
  int g = ((bid & 3) << 2) + (threadIdx.x >> 6);
  int lane = threadIdx.x & 63;
  const u16* slab = Sin + (size_t)q * (NHEAD * N_TOK);

  float4 A0 = {0,0,0,0}, A1 = {0,0,0,0}, A2 = {0,0,0,0}, A3 = {0,0,0,0};
  float4 A4 = {0,0,0,0}, A5 = {0,0,0,0}, A6 = {0,0,0,0}, A7 = {0,0,0,0};
  // premix: h-sequential fmaf (same order as old M1 headmix -> identical keys)
#pragma unroll
  for (int h = 0; h < 16; ++h) {
    float wv = Wpre[g * 16 + h];
    const u16* rowp = slab + (size_t)h * N_TOK + 2 * lane;
#define PM(m, LO, HI) { unsigned pw = *(const unsigned*)(rowp + 128 * (m)); \
      LO = fmaf(wv, b2f((u16)(pw & 0xFFFFu)), LO); \
      HI = fmaf(wv, b2f((u16)(pw >> 16)), HI); }
    ACCS_APPLY(PM)
#undef PM
  }
  // fp32 -> monotone keys (in place of accs)
  uint4 Q0, Q1, Q2, Q3, Q4, Q5, Q6, Q7;
  {
#define NK_IDX(F, AF) F = bits2key(__float_as_uint(AF));
    NK_IDX(Q0.x, A0.x) NK_IDX(Q0.y, A0.y) NK_IDX(Q0.z, A0.z) NK_IDX(Q0.w, A0.w)
    NK_IDX(Q1.x, A1.x) NK_IDX(Q1.y, A1.y) NK_IDX(Q1.z, A1.z) NK_IDX(Q1.w, A1.w)
    NK_IDX(Q2.x, A2.x) NK_IDX(Q2.y, A2.y) NK_IDX(Q2.z, A2.z) NK_IDX(Q2.w, A2.w)
    NK_IDX(Q3.x, A3.x) NK_IDX(Q3.y, A3.y) NK_IDX(Q3.z, A3.z) NK_IDX(Q3.w, A3.w)
    NK_IDX(Q4.x, A4.x) NK_IDX(Q4.y, A4.y) NK_IDX(Q4.z, A4.z) NK_IDX(Q4.w, A4.w)
    NK_IDX(Q5.x, A5.x) NK_IDX(Q5.y, A5.y) NK_IDX(Q5.z, A5.z) NK_IDX(Q5.w, A5.w)
    NK_IDX(Q6.x, A6.x) NK_IDX(Q6.y, A6.y) NK_IDX(Q6.z, A6.z) NK_IDX(Q6.w, A6.w)
    NK_IDX(Q7.x, A7.x) NK_IDX(Q7.y, A7.y) NK_IDX(Q7.z, A7.z) NK_IDX(Q7.w, A7.w)
#undef NK_IDX
  }
  // row max
  unsigned kmax = 0u;
#define MX(KF) kmax = (KF) > kmax ? (KF) : kmax;
  KEYS_APPLY(MX)
#undef MX
#pragma unroll
  for (int d = 32; d >= 1; d >>= 1) {
    unsigned o = (unsigned)__shfl_xor((int)kmax, d);
    kmax = o > kmax ? o : kmax;
  }
  float mx = key2f(kmax);
  // exact 128th-largest key: binary search w/ ballot counting + exact early exit
  unsigned T = 0u;
#pragma unroll 1
  for (int bit = 31; bit >= 0; --bit) {
    unsigned cand = T | (1u << bit);
    int c = 0;
#define CNT(KF) c += (int)__popcll(__ballot((KF) >= cand));
    KEYS_APPLY(CNT)
#undef CNT
    if (c >= TOPK_K) T = cand;
    if (c == TOPK_K) break;
  }
  // z (all) + masked sum (kept: key >= T, ties included)
  float z = 0.f, ms = 0.f;
#define ES(KF) { float ev = __expf(key2f(KF) - mx); z += ev; if ((KF) >= T) ms += ev; }
  KEYS_APPLY(ES)
#undef ES
  z = wave_reduce_sum(z);
  ms = wave_reduce_sum(ms);
  float cs = 1.f / (ms + 1e-9f * z);  // (e/z)/(ms/z+1e-9) = e/(ms+1e-9*z)
  // writeback renormalized attn (bf16)
  u16* op = Sout + ((size_t)q * NHEAD + g) * N_TOK + 2 * lane;
#define WB(m, LO, HI) { \
    float e0 = (LO >= T) ? __expf(key2f(LO) - mx) * cs : 0.f; \
    float e1 = (HI >= T) ? __expf(key2f(HI) - mx) * cs : 0.f; \
    *(unsigned*)(op + 128 * (m)) = (unsigned)f2b(e0) | ((unsigned)f2b(e1) << 16); }
  {
    uint4 A0 = Q0, A1 = Q1, A2 = Q2, A3 = Q3, A4 = Q4, A5 = Q5, A6 = Q6, A7 = Q7;
    ACCS_APPLY(WB)
  }
#undef WB
}

// ---------------- launch ----------------
extern "C" void kernel_launch(void* const* d_in, const int* in_sizes, int n_in,
                              void* d_out, int out_size, void* d_ws, size_t ws_size,
                              hipStream_t stream) {
  const float* x     = (const float*)d_in[0];
  const float* Wq    = (const float*)d_in[1];
  const float* bq    = (const float*)d_in[2];
  const float* Wk    = (const float*)d_in[3];
  const float* bk    = (const float*)d_in[4];
  const float* Wv    = (const float*)d_in[5];
  const float* bv    = (const float*)d_in[6];
  const float* Wpre  = (const float*)d_in[7];
  // d_in[8] = bpre: no-op (softmax shift-invariant; top-k order unchanged)
  const float* Wpost = (const float*)d_in[9];
  const float* bpost = (const float*)d_in[10];
  const float* Wo    = (const float*)d_in[11];
  const float* bo    = (const float*)d_in[12];
  const float* gamma = (const float*)d_in[13];
  const float* beta  = (const float*)d_in[14];

  const size_t NM = (size_t)N_TOK * DMODEL;   // 2M elems
  const size_t WW = (size_t)DMODEL * DMODEL;  // 1M elems
  const int D3 = 3 * DMODEL;                  // 3072
  char* p = (char*)d_ws;
  u16* xnb   = (u16*)p; p += NM * 2;
  u16* QKVb  = (u16*)p; p += (size_t)N_TOK * D3 * 2;  // fused Q|K|V, row stride 3072
  u16* Vtb   = (u16*)p; p += NM * 2;
  u16* AOb   = (u16*)p; p += NM * 2;
  u16* WQKVb = (u16*)p; p += 3 * WW * 2;              // [Wq;Wk;Wv] rows
  u16* Wob   = (u16*)p; p += WW * 2;
  float* bqkv = (float*)p; p += D3 * 4;
  size_t base = (size_t)(p - (char*)d_ws);

  // chunked: per chunk need Sa (scores bf16) + Sb (attn bf16), CQ x 16 x 2048 each
  int CQ = 0;
  const int cands[6] = {2048, 1024, 512, 256, 128, 64};
  for (int i = 0; i < 6; ++i) {
    size_t need = base + (size_t)cands[i] * NHEAD * N_TOK * 4;
    if (need <= ws_size) { CQ = cands[i]; break; }
  }
  if (CQ == 0) return;
  u16* Sa = (u16*)p;
  u16* Sb = (u16*)(p + (size_t)CQ * NHEAD * N_TOK * 2);

  ln_kernel<<<N_TOK / 4, 256, 0, stream>>>(x, gamma, beta, xnb);
  cast_kernel<<<512, 256, 0, stream>>>(Wq, WQKVb, WW / 8);
  cast_kernel<<<512, 256, 0, stream>>>(Wk, WQKVb + WW, WW / 8);
  cast_kernel<<<512, 256, 0, stream>>>(Wv, WQKVb + 2 * WW, WW / 8);
  cast_kernel<<<512, 256, 0, stream>>>(Wo, Wob, WW / 8);
  concat3_kernel<<<12, 256, 0, stream>>>(bq, bk, bv, bqkv);

  // fused QKV projection: QKV = xn @ [Wq;Wk;Wv]^T + [bq;bk;bv]  (bf16, ld 3072)
  gemm_bf16_nt<<<dim3(48, 32, 1), 256, 0, stream>>>(xnb, DMODEL, 0, WQKVb, DMODEL, 0,
                                                    QKVb, D3, 0, DMODEL, 1.f, bqkv, nullptr, 0);
  // Vt from V view (cols 2048.., ld 3072)
  transpose_kernel<<<dim3(N_TOK / 64, DMODEL / 64), 256, 0, stream>>>(QKVb + 2048, D3, Vtb);

  for (int q0 = 0; q0 < N_TOK; q0 += CQ) {
    // scores: Sa[ql][h][k] = 0.125 * Q_h[q0+ql] . K_h^T   (bf16 out)
    gemm_bf16_nt<<<dim3(N_TOK / 64, CQ / 64, NHEAD), 256, 0, stream>>>(
        QKVb + (size_t)q0 * D3, D3, HDK, QKVb + 1024, D3, HDK,
        Sa, NHEAD * N_TOK, N_TOK, HDK, 0.125f, nullptr, nullptr, 0);

    // fused premix + softmax + exact top-128 + renorm -> attn (bf16) into Sb
    premix_topk_kernel<<<CQ * 4, 256, 0, stream>>>(Sa, Wpre, Sb);

    // M3: postmix  attn2[g] = Wpost . attn[h] + bpost  (bf16, in place on Sb)
    headmix_kernel<<<dim3(CQ, 4), 256, 0, stream>>>(Sb, Wpost, bpost, Sb, 0);

    // PV: AO[q0+ql][h*64+d] = attn2[ql][h][:] . Vt_h[d][:]   (bf16 out)
    gemm_bf16_nt<<<dim3(1, CQ / 64, NHEAD), 256, 0, stream>>>(
        Sb, NHEAD * N_TOK, N_TOK, Vtb, N_TOK, HDK * N_TOK,
        AOb + (size_t)q0 * DMODEL, DMODEL, HDK, N_TOK, 1.f, nullptr, nullptr, 0);
  }

  // out = AO @ Wo^T + bo + x   (fp32 out)
  gemm_bf16_nt<<<dim3(16, 32, 1), 256, 0, stream>>>(AOb, DMODEL, 0, Wob, DMODEL, 0,
                                                    d_out, DMODEL, 0, DMODEL, 1.f, bo, x, 1);
}

// Round 10
// 457.216 us; speedup vs baseline: 5.0247x; 1.0646x over previous
//
#include <hip/hip_runtime.h>
#include <stdint.h>

typedef unsigned short u16;
using bf16x8 = __attribute__((ext_vector_type(8))) short;
using f32x4  = __attribute__((ext_vector_type(4))) float;

#define N_TOK 2048
#define DMODEL 1024
#define NHEAD 16
#define HDK 64
#define TOPK_K 128

// ---------------- numeric helpers ----------------
__device__ __forceinline__ u16 f2b(float f) {  // fp32 -> bf16 RNE
  unsigned u = __float_as_uint(f);
  return (u16)((u + 0x7FFFu + ((u >> 16) & 1u)) >> 16);
}
__device__ __forceinline__ float b2f(u16 b) {
  return __uint_as_float(((unsigned)b) << 16);
}
__device__ __forceinline__ float wave_reduce_sum(float v) {
#pragma unroll
  for (int d = 32; d >= 1; d >>= 1) v += __shfl_xor(v, d);
  return v;
}
// order-preserving fp32-bits -> uint key (ascending float -> ascending uint)
__device__ __forceinline__ unsigned bits2key(unsigned u) {
  return (u & 0x80000000u) ? ~u : (u | 0x80000000u);
}
__device__ __forceinline__ float key2f(unsigned k) {
  unsigned u = (k & 0x80000000u) ? (k ^ 0x80000000u) : ~k;
  return __uint_as_float(u);
}

// ---------------- LayerNorm -> bf16 ----------------
__global__ __launch_bounds__(256) void ln_kernel(const float* __restrict__ x,
                                                 const float* __restrict__ gamma,
                                                 const float* __restrict__ beta,
                                                 u16* __restrict__ xn) {
  int w = threadIdx.x >> 6, lane = threadIdx.x & 63;
  int row = blockIdx.x * 4 + w;
  const float4* xr = (const float4*)(x + (size_t)row * DMODEL);
  float4 v[4];
  float s = 0.f, ss = 0.f;
#pragma unroll
  for (int i = 0; i < 4; ++i) {
    v[i] = xr[i * 64 + lane];
    s += v[i].x + v[i].y + v[i].z + v[i].w;
    ss += v[i].x * v[i].x + v[i].y * v[i].y + v[i].z * v[i].z + v[i].w * v[i].w;
  }
  s = wave_reduce_sum(s);
  ss = wave_reduce_sum(ss);
  float mu = s * (1.f / DMODEL);
  float var = ss * (1.f / DMODEL) - mu * mu;
  float rstd = rsqrtf(var + 1e-5f);
  const float4* g4 = (const float4*)gamma;
  const float4* b4 = (const float4*)beta;
  u16* xo = xn + (size_t)row * DMODEL;
#pragma unroll
  for (int i = 0; i < 4; ++i) {
    float4 g = g4[i * 64 + lane], b = b4[i * 64 + lane];
    float ox = (v[i].x - mu) * rstd * g.x + b.x;
    float oy = (v[i].y - mu) * rstd * g.y + b.y;
    float oz = (v[i].z - mu) * rstd * g.z + b.z;
    float ow = (v[i].w - mu) * rstd * g.w + b.w;
    unsigned lo = (unsigned)f2b(ox) | ((unsigned)f2b(oy) << 16);
    unsigned hi = (unsigned)f2b(oz) | ((unsigned)f2b(ow) << 16);
    *(uint2*)&xo[(i * 64 + lane) * 4] = make_uint2(lo, hi);
  }
}

// ---------------- fp32 -> bf16 cast (n8 = elems/8) ----------------
__global__ __launch_bounds__(256) void cast_kernel(const float* __restrict__ in,
                                                   u16* __restrict__ out, int n8) {
  int i = blockIdx.x * 256 + threadIdx.x;
  if (i >= n8) return;
  const float4* p = (const float4*)in + (size_t)i * 2;
  float4 a = p[0], b = p[1];
  unsigned w0 = (unsigned)f2b(a.x) | ((unsigned)f2b(a.y) << 16);
  unsigned w1 = (unsigned)f2b(a.z) | ((unsigned)f2b(a.w) << 16);
  unsigned w2 = (unsigned)f2b(b.x) | ((unsigned)f2b(b.y) << 16);
  unsigned w3 = (unsigned)f2b(b.z) | ((unsigned)f2b(b.w) << 16);
  *(uint4*)&out[(size_t)i * 8] = make_uint4(w0, w1, w2, w3);
}

// ---------------- concat 3 fp32 vectors (1024 each) ----------------
__global__ __launch_bounds__(256) void concat3_kernel(const float* __restrict__ a,
                                                      const float* __restrict__ b,
                                                      const float* __restrict__ c,
                                                      float* __restrict__ out) {
  int i = blockIdx.x * 256 + threadIdx.x;
  if (i < 1024) out[i] = a[i];
  else if (i < 2048) out[i] = b[i - 1024];
  else if (i < 3072) out[i] = c[i - 2048];
}

// ---------------- bf16 transpose with input ld (V view -> Vt 1024x2048) ----------
__global__ __launch_bounds__(256) void transpose_kernel(const u16* __restrict__ V, int ldv,
                                                        u16* __restrict__ Vt) {
  __shared__ u16 tile[64][72];
  int kb = blockIdx.x * 64, cb = blockIdx.y * 64;
  int t = threadIdx.x;
  int r = t >> 2, cg = (t & 3) * 16;
  *(uint4*)&tile[r][cg]     = *(const uint4*)&V[(size_t)(kb + r) * ldv + cb + cg];
  *(uint4*)&tile[r][cg + 8] = *(const uint4*)&V[(size_t)(kb + r) * ldv + cb + cg + 8];
  __syncthreads();
  int c = t >> 2, kg = (t & 3) * 16;
  size_t base = (size_t)(cb + c) * N_TOK + kb + kg;
  unsigned p0 = (unsigned)tile[kg + 0][c] | ((unsigned)tile[kg + 1][c] << 16);
  unsigned p1 = (unsigned)tile[kg + 2][c] | ((unsigned)tile[kg + 3][c] << 16);
  unsigned p2 = (unsigned)tile[kg + 4][c] | ((unsigned)tile[kg + 5][c] << 16);
  unsigned p3 = (unsigned)tile[kg + 6][c] | ((unsigned)tile[kg + 7][c] << 16);
  unsigned p4 = (unsigned)tile[kg + 8][c] | ((unsigned)tile[kg + 9][c] << 16);
  unsigned p5 = (unsigned)tile[kg + 10][c] | ((unsigned)tile[kg + 11][c] << 16);
  unsigned p6 = (unsigned)tile[kg + 12][c] | ((unsigned)tile[kg + 13][c] << 16);
  unsigned p7 = (unsigned)tile[kg + 14][c] | ((unsigned)tile[kg + 15][c] << 16);
  *(uint4*)&Vt[base]     = make_uint4(p0, p1, p2, p3);
  *(uint4*)&Vt[base + 8] = make_uint4(p4, p5, p6, p7);
}

// ---------------- bf16 MFMA GEMM: C = scale*(A . B^T) [+bias] [+res] ----------------
__global__ __launch_bounds__(256) void gemm_bf16_nt(
    const u16* __restrict__ A, int lda, int az,
    const u16* __restrict__ B, int ldb, int bz,
    void* __restrict__ Cv, int ldc, int cz,
    int K, float scale,
    const float* __restrict__ bias,
    const float* __restrict__ res, int out_f32) {
  __shared__ u16 As[64 * 40];  // row stride 40 bf16 (80 B): 16B-aligned, 2-way max
  __shared__ u16 Bs[64 * 40];
  A += (size_t)blockIdx.z * az;
  B += (size_t)blockIdx.z * bz;
  int bi = blockIdx.y * 64, bj = blockIdx.x * 64;
  int tid = threadIdx.x;
  int w = tid >> 6, lane = tid & 63;
  int wr = w >> 1, wc = w & 1;
  int lr = tid >> 2, lc = (tid & 3) * 8;
  int kh = (lane >> 4) * 8, fr = lane & 15;
  f32x4 acc[2][2] = {};
  for (int k0 = 0; k0 < K; k0 += 32) {
    *(uint4*)&As[lr * 40 + lc] = *(const uint4*)&A[(size_t)(bi + lr) * lda + k0 + lc];
    *(uint4*)&Bs[lr * 40 + lc] = *(const uint4*)&B[(size_t)(bj + lr) * ldb + k0 + lc];
    __syncthreads();
    bf16x8 a0 = *(bf16x8*)&As[(wr * 32 + fr) * 40 + kh];
    bf16x8 a1 = *(bf16x8*)&As[(wr * 32 + 16 + fr) * 40 + kh];
    bf16x8 b0 = *(bf16x8*)&Bs[(wc * 32 + fr) * 40 + kh];
    bf16x8 b1 = *(bf16x8*)&Bs[(wc * 32 + 16 + fr) * 40 + kh];
    acc[0][0] = __builtin_amdgcn_mfma_f32_16x16x32_bf16(a0, b0, acc[0][0], 0, 0, 0);
    acc[0][1] = __builtin_amdgcn_mfma_f32_16x16x32_bf16(a0, b1, acc[0][1], 0, 0, 0);
    acc[1][0] = __builtin_amdgcn_mfma_f32_16x16x32_bf16(a1, b0, acc[1][0], 0, 0, 0);
    acc[1][1] = __builtin_amdgcn_mfma_f32_16x16x32_bf16(a1, b1, acc[1][1], 0, 0, 0);
    __syncthreads();
  }
  float* Cf = (float*)Cv + (size_t)blockIdx.z * cz;
  u16* Ch = (u16*)Cv + (size_t)blockIdx.z * cz;
  int rg = (lane >> 4) * 4;
#pragma unroll
  for (int m = 0; m < 2; ++m) {
#pragma unroll
    for (int n = 0; n < 2; ++n) {
      int gcol = bj + wc * 32 + n * 16 + fr;
      float badd = bias ? bias[gcol] : 0.f;
#pragma unroll
      for (int r = 0; r < 4; ++r) {
        int grow = bi + wr * 32 + m * 16 + rg + r;
        size_t off = (size_t)grow * ldc + gcol;
        float v = acc[m][n][r] * scale + badd;
        if (res) v += res[off];
        if (out_f32) Cf[off] = v;
        else Ch[off] = f2b(v);
      }
    }
  }
}

// ------- fused premix + softmax + exact top-128 + renorm + postmix (in place) -------
// One BLOCK per query q (16 waves). Phase 1: wave g does premix+topk+renorm for row
// (q,g) exactly as round 9 (named-register keys), writes bf16 attn row into LDS.
// Phase 2 (after syncthreads): wave w owns a 128-col stripe of all 16 output rows:
// 16 LDS reads + 16x16 fmaf postmix (+bpost), writes attn2 IN PLACE over S's q-slab
// (safe: the whole slab was consumed by this block in phase 1).
#define ACCS_APPLY(OP) \
  OP(0, A0.x, A0.y)  OP(1, A0.z, A0.w)  OP(2, A1.x, A1.y)  OP(3, A1.z, A1.w) \
  OP(4, A2.x, A2.y)  OP(5, A2.z, A2.w)  OP(6, A3.x, A3.y)  OP(7, A3.z, A3.w) \
  OP(8, A4.x, A4.y)  OP(9, A4.z, A4.w)  OP(10, A5.x, A5.y) OP(11, A5.z, A5.w) \
  OP(12, A6.x, A6.y) OP(13, A6.z, A6.w) OP(14, A7.x, A7.y) OP(15, A7.z, A7.w)
#define KEYS_APPLY(OP) \
  OP(Q0.x) OP(Q0.y) OP(Q0.z) OP(Q0.w) OP(Q1.x) OP(Q1.y) OP(Q1.z) OP(Q1.w) \
  OP(Q2.x) OP(Q2.y) OP(Q2.z) OP(Q2.w) OP(Q3.x) OP(Q3.y) OP(Q3.z) OP(Q3.w) \
  OP(Q4.x) OP(Q4.y) OP(Q4.z) OP(Q4.w) OP(Q5.x) OP(Q5.y) OP(Q5.z) OP(Q5.w) \
  OP(Q6.x) OP(Q6.y) OP(Q6.z) OP(Q6.w) OP(Q7.x) OP(Q7.y) OP(Q7.z) OP(Q7.w)
#define BACC_APPLY(OP) \
  OP(0, B0.x, B0.y)  OP(1, B0.z, B0.w)  OP(2, B1.x, B1.y)  OP(3, B1.z, B1.w) \
  OP(4, B2.x, B2.y)  OP(5, B2.z, B2.w)  OP(6, B3.x, B3.y)  OP(7, B3.z, B3.w) \
  OP(8, B4.x, B4.y)  OP(9, B4.z, B4.w)  OP(10, B5.x, B5.y) OP(11, B5.z, B5.w) \
  OP(12, B6.x, B6.y) OP(13, B6.z, B6.w) OP(14, B7.x, B7.y) OP(15, B7.z, B7.w)

__global__ __launch_bounds__(1024, 4) void premix_topk_post_kernel(
    u16* __restrict__ S, const float* __restrict__ Wpre,
    const float* __restrict__ Wpost, const float* __restrict__ bpost) {
  __shared__ u16 attn_lds[NHEAD][N_TOK];  // 64 KB
  __shared__ float w2_s[256], b2_s[16];
  int q = blockIdx.x;
  int g = threadIdx.x >> 6;
  int lane = threadIdx.x & 63;
  int tid = threadIdx.x;
  if (tid < 256) w2_s[tid] = Wpost[tid];
  else if (tid < 272) b2_s[tid - 256] = bpost[tid - 256];
  u16* slab = S + (size_t)q * (NHEAD * N_TOK);

  // ---- phase 1: premix + topk + renorm (per-wave, identical to round 9) ----
  float4 A0 = {0,0,0,0}, A1 = {0,0,0,0}, A2 = {0,0,0,0}, A3 = {0,0,0,0};
  float4 A4 = {0,0,0,0}, A5 = {0,0,0,0}, A6 = {0,0,0,0}, A7 = {0,0,0,0};
#pragma unroll
  for (int h = 0; h < 16; ++h) {
    float wv = Wpre[g * 16 + h];
    const u16* rowp = slab + (size_t)h * N_TOK + 2 * lane;
#define PM(m, LO, HI) { unsigned pw = *(const unsigned*)(rowp + 128 * (m)); \
      LO = fmaf(wv, b2f((u16)(pw & 0xFFFFu)), LO); \
      HI = fmaf(wv, b2f((u16)(pw >> 16)), HI); }
    ACCS_APPLY(PM)
#undef PM
  }
  uint4 Q0, Q1, Q2, Q3, Q4, Q5, Q6, Q7;
  {
#define NK_IDX(F, AF) F = bits2key(__float_as_uint(AF));
    NK_IDX(Q0.x, A0.x) NK_IDX(Q0.y, A0.y) NK_IDX(Q0.z, A0.z) NK_IDX(Q0.w, A0.w)
    NK_IDX(Q1.x, A1.x) NK_IDX(Q1.y, A1.y) NK_IDX(Q1.z, A1.z) NK_IDX(Q1.w, A1.w)
    NK_IDX(Q2.x, A2.x) NK_IDX(Q2.y, A2.y) NK_IDX(Q2.z, A2.z) NK_IDX(Q2.w, A2.w)
    NK_IDX(Q3.x, A3.x) NK_IDX(Q3.y, A3.y) NK_IDX(Q3.z, A3.z) NK_IDX(Q3.w, A3.w)
    NK_IDX(Q4.x, A4.x) NK_IDX(Q4.y, A4.y) NK_IDX(Q4.z, A4.z) NK_IDX(Q4.w, A4.w)
    NK_IDX(Q5.x, A5.x) NK_IDX(Q5.y, A5.y) NK_IDX(Q5.z, A5.z) NK_IDX(Q5.w, A5.w)
    NK_IDX(Q6.x, A6.x) NK_IDX(Q6.y, A6.y) NK_IDX(Q6.z, A6.z) NK_IDX(Q6.w, A6.w)
    NK_IDX(Q7.x, A7.x) NK_IDX(Q7.y, A7.y) NK_IDX(Q7.z, A7.z) NK_IDX(Q7.w, A7.w)
#undef NK_IDX
  }
  unsigned kmax = 0u;
#define MX(KF) kmax = (KF) > kmax ? (KF) : kmax;
  KEYS_APPLY(MX)
#undef MX
#pragma unroll
  for (int d = 32; d >= 1; d >>= 1) {
    unsigned o = (unsigned)__shfl_xor((int)kmax, d);
    kmax = o > kmax ? o : kmax;
  }
  float mx = key2f(kmax);
  unsigned T = 0u;
#pragma unroll 1
  for (int bit = 31; bit >= 0; --bit) {
    unsigned cand = T | (1u << bit);
    int c = 0;
#define CNT(KF) c += (int)__popcll(__ballot((KF) >= cand));
    KEYS_APPLY(CNT)
#undef CNT
    if (c >= TOPK_K) T = cand;
    if (c == TOPK_K) break;
  }
  float z = 0.f, ms = 0.f;
#define ES(KF) { float ev = __expf(key2f(KF) - mx); z += ev; if ((KF) >= T) ms += ev; }
  KEYS_APPLY(ES)
#undef ES
  z = wave_reduce_sum(z);
  ms = wave_reduce_sum(ms);
  float cs = 1.f / (ms + 1e-9f * z);
  // write renormalized attn (bf16) into LDS row g
  u16* lp = &attn_lds[g][2 * lane];
#define WB(m, LO, HI) { \
    float e0 = (LO >= T) ? __expf(key2f(LO) - mx) * cs : 0.f; \
    float e1 = (HI >= T) ? __expf(key2f(HI) - mx) * cs : 0.f; \
    *(unsigned*)(lp + 128 * (m)) = (unsigned)f2b(e0) | ((unsigned)f2b(e1) << 16); }
  {
    uint4 A0 = Q0, A1 = Q1, A2 = Q2, A3 = Q3, A4 = Q4, A5 = Q5, A6 = Q6, A7 = Q7;
    ACCS_APPLY(WB)
  }
#undef WB
  __syncthreads();

  // ---- phase 2: postmix stripe — wave w owns cols [w*128, w*128+128) of all g ----
  int cb = g * 128 + 2 * lane;  // reuse wave id as stripe id
  float4 B0, B1, B2, B3, B4, B5, B6, B7;
#define BI(gg, LO, HI) LO = b2_s[gg]; HI = b2_s[gg];
  BACC_APPLY(BI)
#undef BI
#pragma unroll
  for (int h = 0; h < 16; ++h) {
    unsigned pw = *(const unsigned*)&attn_lds[h][cb];
    float lo_ = b2f((u16)(pw & 0xFFFFu));
    float hi_ = b2f((u16)(pw >> 16));
#define BM(gg, LO, HI) { float wv = w2_s[(gg) * 16 + h]; \
      LO = fmaf(wv, lo_, LO); HI = fmaf(wv, hi_, HI); }
    BACC_APPLY(BM)
#undef BM
  }
#define BW(gg, LO, HI) \
  *(unsigned*)(slab + (size_t)(gg) * N_TOK + cb) = \
      (unsigned)f2b(LO) | ((unsigned)f2b(HI) << 16);
  BACC_APPLY(BW)
#undef BW
}

// ---------------- launch ----------------
extern "C" void kernel_launch(void* const* d_in, const int* in_sizes, int n_in,
                              void* d_out, int out_size, void* d_ws, size_t ws_size,
                              hipStream_t stream) {
  const float* x     = (const float*)d_in[0];
  const float* Wq    = (const float*)d_in[1];
  const float* bq    = (const float*)d_in[2];
  const float* Wk    = (const float*)d_in[3];
  const float* bk    = (const float*)d_in[4];
  const float* Wv    = (const float*)d_in[5];
  const float* bv    = (const float*)d_in[6];
  const float* Wpre  = (const float*)d_in[7];
  // d_in[8] = bpre: no-op (softmax shift-invariant; top-k order unchanged)
  const float* Wpost = (const float*)d_in[9];
  const float* bpost = (const float*)d_in[10];
  const float* Wo    = (const float*)d_in[11];
  const float* bo    = (const float*)d_in[12];
  const float* gamma = (const float*)d_in[13];
  const float* beta  = (const float*)d_in[14];

  const size_t NM = (size_t)N_TOK * DMODEL;   // 2M elems
  const size_t WW = (size_t)DMODEL * DMODEL;  // 1M elems
  const int D3 = 3 * DMODEL;                  // 3072
  char* p = (char*)d_ws;
  u16* xnb   = (u16*)p; p += NM * 2;
  u16* QKVb  = (u16*)p; p += (size_t)N_TOK * D3 * 2;  // fused Q|K|V, row stride 3072
  u16* Vtb   = (u16*)p; p += NM * 2;
  u16* AOb   = (u16*)p; p += NM * 2;
  u16* WQKVb = (u16*)p; p += 3 * WW * 2;              // [Wq;Wk;Wv] rows
  u16* Wob   = (u16*)p; p += WW * 2;
  float* bqkv = (float*)p; p += D3 * 4;
  size_t base = (size_t)(p - (char*)d_ws);

  // chunked: per chunk need S (scores->attn2 in place, bf16) of CQ x 16 x 2048
  int CQ = 0;
  const int cands[6] = {2048, 1024, 512, 256, 128, 64};
  for (int i = 0; i < 6; ++i) {
    size_t need = base + (size_t)cands[i] * NHEAD * N_TOK * 2;
    if (need <= ws_size) { CQ = cands[i]; break; }
  }
  if (CQ == 0) return;
  u16* S = (u16*)p;

  ln_kernel<<<N_TOK / 4, 256, 0, stream>>>(x, gamma, beta, xnb);
  cast_kernel<<<512, 256, 0, stream>>>(Wq, WQKVb, WW / 8);
  cast_kernel<<<512, 256, 0, stream>>>(Wk, WQKVb + WW, WW / 8);
  cast_kernel<<<512, 256, 0, stream>>>(Wv, WQKVb + 2 * WW, WW / 8);
  cast_kernel<<<512, 256, 0, stream>>>(Wo, Wob, WW / 8);
  concat3_kernel<<<12, 256, 0, stream>>>(bq, bk, bv, bqkv);

  // fused QKV projection: QKV = xn @ [Wq;Wk;Wv]^T + [bq;bk;bv]  (bf16, ld 3072)
  gemm_bf16_nt<<<dim3(48, 32, 1), 256, 0, stream>>>(xnb, DMODEL, 0, WQKVb, DMODEL, 0,
                                                    QKVb, D3, 0, DMODEL, 1.f, bqkv, nullptr, 0);
  // Vt from V view (cols 2048.., ld 3072)
  transpose_kernel<<<dim3(N_TOK / 64, DMODEL / 64), 256, 0, stream>>>(QKVb + 2048, D3, Vtb);

  for (int q0 = 0; q0 < N_TOK; q0 += CQ) {
    // scores: S[ql][h][k] = 0.125 * Q_h[q0+ql] . K_h^T   (bf16 out)
    gemm_bf16_nt<<<dim3(N_TOK / 64, CQ / 64, NHEAD), 256, 0, stream>>>(
        QKVb + (size_t)q0 * D3, D3, HDK, QKVb + 1024, D3, HDK,
        S, NHEAD * N_TOK, N_TOK, HDK, 0.125f, nullptr, nullptr, 0);

    // fused premix + topk + renorm + postmix (attn2 in place over S)
    premix_topk_post_kernel<<<CQ, 1024, 0, stream>>>(S, Wpre, Wpost, bpost);

    // PV: AO[q0+ql][h*64+d] = attn2[ql][h][:] . Vt_h[d][:]   (bf16 out)
    gemm_bf16_nt<<<dim3(1, CQ / 64, NHEAD), 256, 0, stream>>>(
        S, NHEAD * N_TOK, N_TOK, Vtb, N_TOK, HDK * N_TOK,
        AOb + (size_t)q0 * DMODEL, DMODEL, HDK, N_TOK, 1.f, nullptr, nullptr, 0);
  }

  // out = AO @ Wo^T + bo + x   (fp32 out)
  gemm_bf16_nt<<<dim3(16, 32, 1), 256, 0, stream>>>(AOb, DMODEL, 0, Wob, DMODEL, 0,
                                                    d_out, DMODEL, 0, DMODEL, 1.f, bo, x, 1);
}